// Round 9
// baseline (266.903 us; speedup 1.0000x reference)
//
#include <hip/hip_runtime.h>
#include <stdint.h>

#define BATCH 4
#define SEQ   2048
#define FDIM  512
#define NHEAD 8
#define HDIM  64
#define KNN   32

typedef unsigned int u32;
typedef unsigned long long u64;
typedef unsigned short u16;
typedef unsigned short bf16_t;

typedef __attribute__((ext_vector_type(8))) short short8;   // 8 bf16 = 4 VGPRs
typedef __attribute__((ext_vector_type(4))) float f32x4;

#define SF  ((size_t)SEQ * FDIM)            // 1,048,576 per-batch elements
#define BSF ((size_t)BATCH * SF)            // 4,194,304

__device__ __forceinline__ bf16_t f2bf(float f) {
    u32 x = __float_as_uint(f);
    return (bf16_t)((x + 0x7FFFu + ((x >> 16) & 1u)) >> 16);   // RNE
}
__device__ __forceinline__ float bf2f(bf16_t u) { return __uint_as_float(((u32)u) << 16); }
__device__ __forceinline__ void bf2x2(u32 p, float& a, float& b) {
    a = __uint_as_float(p << 16);          // element 2i (low u16)
    b = __uint_as_float(p & 0xFFFF0000u);  // element 2i+1 (high u16)
}

__device__ __forceinline__ u64 shfl_xor_u64(u64 v, int m) {
    int lo = __shfl_xor((int)(u32)v, m, 64);
    int hi = __shfl_xor((int)(u32)(v >> 32), m, 64);
    return (((u64)(u32)hi) << 32) | (u32)lo;
}
__device__ __forceinline__ u64 min_u64(u64 a, u64 b) { return a < b ? a : b; }

// ---------------------------------------------------------------------------
// Cast x / Wq / Wk / Wv (fp32) -> bf16, 8 elements/thread. grid.z selects.
// ---------------------------------------------------------------------------
__global__ __launch_bounds__(256) void cast_kernel(const float* __restrict__ x,
                                                   const float* __restrict__ wq,
                                                   const float* __restrict__ wk,
                                                   const float* __restrict__ wv,
                                                   bf16_t* __restrict__ xb,
                                                   bf16_t* __restrict__ wqb,
                                                   bf16_t* __restrict__ wkb,
                                                   bf16_t* __restrict__ wvb) {
    const int z = blockIdx.z;
    const float* src = (z == 0) ? x : (z == 1) ? wq : (z == 2) ? wk : wv;
    bf16_t* dst      = (z == 0) ? xb : (z == 1) ? wqb : (z == 2) ? wkb : wvb;
    const size_t cnt8 = (z == 0) ? (BSF / 8) : ((size_t)FDIM * FDIM / 8);
    size_t idx = (size_t)blockIdx.x * 256 + threadIdx.x;
    if (idx >= cnt8) return;
    const float4 a = ((const float4*)src)[idx * 2 + 0];
    const float4 b = ((const float4*)src)[idx * 2 + 1];
    uint4 o;
    o.x = (u32)f2bf(a.x) | ((u32)f2bf(a.y) << 16);
    o.y = (u32)f2bf(a.z) | ((u32)f2bf(a.w) << 16);
    o.z = (u32)f2bf(b.x) | ((u32)f2bf(b.y) << 16);
    o.w = (u32)f2bf(b.z) | ((u32)f2bf(b.w) << 16);
    ((uint4*)dst)[idx] = o;
}

// ---------------------------------------------------------------------------
// kNN: one block (256 thr = 4 waves) per query. Each thread sorts 8
// candidates (u64 key = (dist_bits<<32)|idx, numpy-exact distance) into LDS;
// waves 1-3 exit; wave 0 merges 4 lists/lane via 33 successive-unique-min
// extraction rounds (identical semantics to the round-6/7/8 proven kernel:
// stable argsort incl. self at rank 0, dropped).
// ---------------------------------------------------------------------------
__global__ __launch_bounds__(256) void knn_kernel(const float* __restrict__ coords,
                                                  u16* __restrict__ nn_out) {
    __shared__ u64 lists[8 * 256];        // [pos][thread], 16 KB
    const int blk = blockIdx.x;           // b*SEQ + qi
    const int b   = blk >> 11;
    const int qi  = blk & (SEQ - 1);
    const int t   = threadIdx.x;

    const float* cb = coords + (size_t)b * SEQ * 3;
    const float qx = cb[qi * 3 + 0];
    const float qy = cb[qi * 3 + 1];
    const float qz = cb[qi * 3 + 2];

    u64 key[8];
#pragma unroll
    for (int i = 0; i < 8; ++i) {
        int c = i * 256 + t;
        float dx = __fsub_rn(cb[c * 3 + 0], qx);
        float dy = __fsub_rn(cb[c * 3 + 1], qy);
        float dz = __fsub_rn(cb[c * 3 + 2], qz);
        // numpy order: (dx*dx + dy*dy) + dz*dz, no FMA contraction, IEEE sqrt
        float d2 = __fadd_rn(__fadd_rn(__fmul_rn(dx, dx), __fmul_rn(dy, dy)),
                             __fmul_rn(dz, dz));
        float dist = __fsqrt_rn(d2);
        key[i] = (((u64)__float_as_uint(dist)) << 32) | (u32)c;   // self included
    }

    // per-thread bitonic sort of 8, ascending, fully unrolled
#pragma unroll
    for (int k = 2; k <= 8; k <<= 1) {
#pragma unroll
        for (int j = k >> 1; j > 0; j >>= 1) {
#pragma unroll
            for (int i = 0; i < 8; ++i) {
                int ixj = i ^ j;
                if (ixj > i) {
                    bool up = (i & k) == 0;
                    u64 a = key[i], c2 = key[ixj];
                    bool sw = up ? (a > c2) : (a < c2);
                    u64 lo = sw ? c2 : a;
                    u64 hi = sw ? a : c2;
                    key[i] = lo;
                    key[ixj] = hi;
                }
            }
        }
    }

#pragma unroll
    for (int i = 0; i < 8; ++i) lists[i * 256 + t] = key[i];
    __syncthreads();

    if (t >= 64) return;                  // waves 1..3 done; wave 0 extracts
    const int lane = t;

    u64 h[4]; int p[4];
#pragma unroll
    for (int w = 0; w < 4; ++w) { h[w] = lists[lane + 64 * w]; p[w] = 1; }

    u32 my = 0;
#pragma unroll 1
    for (int r = 0; r < KNN + 1; ++r) {   // rank 0 = self slot, dropped
        u64 m = min_u64(min_u64(h[0], h[1]), min_u64(h[2], h[3]));
        m = min_u64(m, shfl_xor_u64(m, 1));
        m = min_u64(m, shfl_xor_u64(m, 2));
        m = min_u64(m, shfl_xor_u64(m, 4));
        m = min_u64(m, shfl_xor_u64(m, 8));
        m = min_u64(m, shfl_xor_u64(m, 16));
        m = min_u64(m, shfl_xor_u64(m, 32));
        if (r == lane + 1) my = (u32)m;   // lane j captures rank j+1
#pragma unroll
        for (int w = 0; w < 4; ++w) {
            if (h[w] == m) {              // unique winner (idx embedded in key)
                h[w] = (p[w] < 8) ? lists[p[w] * 256 + lane + 64 * w] : ~0ull;
                ++p[w];
            }
        }
    }
    if (lane < KNN) nn_out[(size_t)blk * KNN + lane] = (u16)(my & 0x7FF);
}

// ---------------------------------------------------------------------------
// LDS-tiled MFMA GEMM (m93 structure): out[m,n] = sum_k A[m,k]*W[n,k].
// 128x128 block tile, BK=32, 256 thr = 4 waves (2x2), 64x64 wave tile,
// 4x4 grid of 16x16x32 MFMAs, fp32 acc. VGPR-staged LDS (16 KB).
// z=0 -> q (fp32 to d_out); z=1,2 -> k,v (bf16 to ws).
// ---------------------------------------------------------------------------
__global__ __launch_bounds__(256) void gemm_mfma(const bf16_t* __restrict__ xb,
                                                 const bf16_t* __restrict__ wqb,
                                                 const bf16_t* __restrict__ wkb,
                                                 const bf16_t* __restrict__ wvb,
                                                 float* __restrict__ qout,
                                                 bf16_t* __restrict__ kvout) {
    __shared__ __align__(16) bf16_t As[128 * 32];
    __shared__ __align__(16) bf16_t Bs[128 * 32];
    const int z = blockIdx.z;
    const bf16_t* W = (z == 0) ? wqb : (z == 1) ? wkb : wvb;
    const int tid  = threadIdx.x;
    const int wid  = tid >> 6, lane = tid & 63;
    const int m16  = lane & 15, quad = lane >> 4;
    const int wm   = (wid & 1) * 64;          // wave M-offset in tile
    const int wn   = (wid >> 1) * 64;         // wave N-offset in tile
    const int m0   = blockIdx.y * 128;
    const int n0   = blockIdx.x * 128;

    const int sr = tid >> 2, sc = (tid & 3) * 8;
    const bf16_t* agp = xb + (size_t)(m0 + sr) * FDIM + sc;
    const bf16_t* bgp = W  + (size_t)(n0 + sr) * FDIM + sc;

    f32x4 acc[4][4];
#pragma unroll
    for (int i = 0; i < 4; ++i)
#pragma unroll
        for (int j = 0; j < 4; ++j) acc[i][j] = (f32x4){0.f, 0.f, 0.f, 0.f};

#pragma unroll 1
    for (int k0 = 0; k0 < FDIM; k0 += 32) {
        uint4 a0 = *(const uint4*)(agp + k0);
        uint4 a1 = *(const uint4*)(agp + (size_t)64 * FDIM + k0);
        uint4 b0 = *(const uint4*)(bgp + k0);
        uint4 b1 = *(const uint4*)(bgp + (size_t)64 * FDIM + k0);
        __syncthreads();
        *(uint4*)(As + sr * 32 + sc)        = a0;
        *(uint4*)(As + (sr + 64) * 32 + sc) = a1;
        *(uint4*)(Bs + sr * 32 + sc)        = b0;
        *(uint4*)(Bs + (sr + 64) * 32 + sc) = b1;
        __syncthreads();

        short8 af[4], bfr[4];
#pragma unroll
        for (int i = 0; i < 4; ++i)
            af[i] = *(const short8*)(As + (wm + i * 16 + m16) * 32 + quad * 8);
#pragma unroll
        for (int j = 0; j < 4; ++j)
            bfr[j] = *(const short8*)(Bs + (wn + j * 16 + m16) * 32 + quad * 8);
#pragma unroll
        for (int i = 0; i < 4; ++i)
#pragma unroll
            for (int j = 0; j < 4; ++j)
                acc[i][j] = __builtin_amdgcn_mfma_f32_16x16x32_bf16(af[i], bfr[j],
                                                                    acc[i][j], 0, 0, 0);
    }

    if (z == 0) {
#pragma unroll
        for (int i = 0; i < 4; ++i) {
            const int rowb = m0 + wm + i * 16 + quad * 4;
#pragma unroll
            for (int r = 0; r < 4; ++r) {
                float* orow = qout + (size_t)(rowb + r) * FDIM + n0 + wn + m16;
                orow[ 0] = acc[i][0][r]; orow[16] = acc[i][1][r];
                orow[32] = acc[i][2][r]; orow[48] = acc[i][3][r];
            }
        }
    } else {
        bf16_t* base = kvout + (size_t)(z - 1) * BSF;
#pragma unroll
        for (int i = 0; i < 4; ++i) {
            const int rowb = m0 + wm + i * 16 + quad * 4;
#pragma unroll
            for (int r = 0; r < 4; ++r) {
                bf16_t* orow = base + (size_t)(rowb + r) * FDIM + n0 + wn + m16;
                orow[ 0] = f2bf(acc[i][0][r]); orow[16] = f2bf(acc[i][1][r]);
                orow[32] = f2bf(acc[i][2][r]); orow[48] = f2bf(acc[i][3][r]);
            }
        }
    }
}

// ---------------------------------------------------------------------------
// Attention, ALL batches: block per (b,q), 512 thr = 8 waves, wave per head.
// kv bf16 = [k_all | v_all] in ws. q read fp32 from d_out (own row), then
// overwritten with the result.
// ---------------------------------------------------------------------------
__global__ __launch_bounds__(512) void attn_kernel(const bf16_t* __restrict__ kv,
                                                   const u16* __restrict__ nn,
                                                   float* __restrict__ out) {
    __shared__ float qs[FDIM];
    __shared__ int   sidx[KNN];
    __shared__ float wls[NHEAD][KNN];
    const int blk = blockIdx.x;            // b*SEQ + q
    const int b   = blk >> 11;
    const int tid = threadIdx.x;
    const int h = tid >> 6, lane = tid & 63;

    qs[tid] = out[(size_t)blk * FDIM + tid];                  // own q row
    if (tid < KNN) sidx[tid] = (int)nn[(size_t)blk * KNN + tid] & (SEQ - 1);
    __syncthreads();

    const int j = lane & 31, half = lane >> 5;
    const bf16_t* kreg = kv + ((size_t)((b << 11) + sidx[j])) * FDIM + h * HDIM + half * 32;
    const float* qp = &qs[h * HDIM + half * 32];
    float acc = 0.f;
#pragma unroll
    for (int d = 0; d < 32; d += 8) {
        uint4 kvv = *(const uint4*)(kreg + d);   // 8 bf16
        float f0, f1, f2, f3, f4, f5, f6, f7;
        bf2x2(kvv.x, f0, f1); bf2x2(kvv.y, f2, f3);
        bf2x2(kvv.z, f4, f5); bf2x2(kvv.w, f6, f7);
        acc += qp[d + 0] * f0 + qp[d + 1] * f1 + qp[d + 2] * f2 + qp[d + 3] * f3
             + qp[d + 4] * f4 + qp[d + 5] * f5 + qp[d + 6] * f6 + qp[d + 7] * f7;
    }
    acc += __shfl_xor(acc, 32, 64);
    float s = acc * 0.125f;                 // 1/sqrt(64)
    float m = s;
    m = fmaxf(m, __shfl_xor(m, 1, 64));
    m = fmaxf(m, __shfl_xor(m, 2, 64));
    m = fmaxf(m, __shfl_xor(m, 4, 64));
    m = fmaxf(m, __shfl_xor(m, 8, 64));
    m = fmaxf(m, __shfl_xor(m, 16, 64));
    float e = __expf(s - m);
    float sum = e;
    sum += __shfl_xor(sum, 1, 64);
    sum += __shfl_xor(sum, 2, 64);
    sum += __shfl_xor(sum, 4, 64);
    sum += __shfl_xor(sum, 8, 64);
    sum += __shfl_xor(sum, 16, 64);
    float w = e / sum;
    if (half == 0) wls[h][j] = w;
    __syncthreads();

    const bf16_t* vb = kv + BSF + ((size_t)(b << 11)) * FDIM + h * HDIM + lane;
    float o = 0.f;
#pragma unroll 4
    for (int j2 = 0; j2 < KNN; ++j2) {
        o += wls[h][j2] * bf2f(vb[(size_t)sidx[j2] * FDIM]);
    }
    out[(size_t)blk * FDIM + h * HDIM + lane] = o;
}

// ---------------------------------------------------------------------------
// metric = mean_s(k) = (mean_s x) @ Wk^T  (linearity), fp32 from raw inputs
// ---------------------------------------------------------------------------
__global__ __launch_bounds__(256) void xbar_kernel(const float* __restrict__ x,
                                                   float* __restrict__ xbar) {
    const int b = blockIdx.x, chunk = blockIdx.y;   // 32 chunks of 64 rows
    const int tid = threadIdx.x;
    const float* xp = x + (size_t)b * SF + (size_t)chunk * 64 * FDIM;
    float s0 = 0.f, s1 = 0.f;
    for (int r = 0; r < 64; ++r) {
        s0 += xp[(size_t)r * FDIM + tid];
        s1 += xp[(size_t)r * FDIM + tid + 256];
    }
    atomicAdd(&xbar[b * FDIM + tid],       s0 * (1.f / 2048.f));
    atomicAdd(&xbar[b * FDIM + tid + 256], s1 * (1.f / 2048.f));
}

__global__ __launch_bounds__(256) void metric_kernel(const float* __restrict__ xbar,
                                                     const float* __restrict__ Wk,
                                                     float* __restrict__ metric) {
    const int o = blockIdx.x * 256 + threadIdx.x;   // 2048 outputs
    const int b = o >> 9, f = o & 511;
    const float* xb = xbar + b * FDIM;
    const float* wr = Wk + (size_t)f * FDIM;
    float acc = 0.f;
#pragma unroll 4
    for (int kk = 0; kk < FDIM; kk += 4) {
        float4 wv = *(const float4*)(wr + kk);
        acc += xb[kk + 0] * wv.x + xb[kk + 1] * wv.y
             + xb[kk + 2] * wv.z + xb[kk + 3] * wv.w;
    }
    metric[o] = acc;
}

// ---------------------------------------------------------------------------
extern "C" void kernel_launch(void* const* d_in, const int* in_sizes, int n_in,
                              void* d_out, int out_size, void* d_ws, size_t ws_size,
                              hipStream_t stream) {
    const float* x      = (const float*)d_in[0];
    const float* coords = (const float*)d_in[1];
    const float* Wq     = (const float*)d_in[2];
    const float* Wk     = (const float*)d_in[3];
    const float* Wv     = (const float*)d_in[4];
    float* out    = (float*)d_out;
    float* metric = out + BSF;

    // ws layout (26.0 MiB):
    //   xb bf16 BSF (8 MiB) | wqb/wkb/wvb bf16 (1.5 MiB) | kv bf16 2*BSF (16 MiB)
    //   | nn u16 (0.5 MiB) | xbar f32 (8 KiB)
    char* p = (char*)d_ws;
    bf16_t* xb   = (bf16_t*)p;                       p += BSF * sizeof(bf16_t);
    bf16_t* wqb  = (bf16_t*)p;                       p += (size_t)FDIM * FDIM * sizeof(bf16_t);
    bf16_t* wkb  = (bf16_t*)p;                       p += (size_t)FDIM * FDIM * sizeof(bf16_t);
    bf16_t* wvb  = (bf16_t*)p;                       p += (size_t)FDIM * FDIM * sizeof(bf16_t);
    bf16_t* kv   = (bf16_t*)p;                       p += 2 * BSF * sizeof(bf16_t);
    u16*    nn   = (u16*)p;                          p += (size_t)BATCH * SEQ * KNN * sizeof(u16);
    float*  xbar = (float*)p;

    cast_kernel<<<dim3(BSF / 8 / 256, 1, 4), 256, 0, stream>>>(x, Wq, Wk, Wv,
                                                               xb, wqb, wkb, wvb);
    knn_kernel<<<BATCH * SEQ, 256, 0, stream>>>(coords, nn);

    // q -> d_out (fp32), k/v -> ws (bf16); one dispatch, 128x128 tiles
    gemm_mfma<<<dim3(FDIM / 128, (BATCH * SEQ) / 128, 3), 256, 0, stream>>>(
        xb, wqb, wkb, wvb, out, kv);

    hipMemsetAsync(xbar, 0, BATCH * FDIM * sizeof(float), stream);
    xbar_kernel<<<dim3(BATCH, 32), 256, 0, stream>>>(x, xbar);
    metric_kernel<<<(BATCH * NHEAD * HDIM) / 256, 256, 0, stream>>>(xbar, Wk, metric);

    attn_kernel<<<BATCH * SEQ, 512, 0, stream>>>(kv, nn, out);
}

// Round 10
// 250.570 us; speedup vs baseline: 1.0652x; 1.0652x over previous
//
#include <hip/hip_runtime.h>
#include <stdint.h>

#define BATCH 4
#define SEQ   2048
#define FDIM  512
#define NHEAD 8
#define HDIM  64
#define KNN   32

typedef unsigned int u32;
typedef unsigned long long u64;
typedef unsigned short u16;
typedef unsigned short bf16_t;

typedef __attribute__((ext_vector_type(8))) short short8;   // 8 bf16 = 4 VGPRs
typedef __attribute__((ext_vector_type(4))) float f32x4;

#define SF  ((size_t)SEQ * FDIM)            // 1,048,576 per-batch elements
#define BSF ((size_t)BATCH * SF)            // 4,194,304

__device__ __forceinline__ bf16_t f2bf(float f) {
    u32 x = __float_as_uint(f);
    return (bf16_t)((x + 0x7FFFu + ((x >> 16) & 1u)) >> 16);   // RNE
}
__device__ __forceinline__ float bf2f(bf16_t u) { return __uint_as_float(((u32)u) << 16); }
__device__ __forceinline__ void bf2x2(u32 p, float& a, float& b) {
    a = __uint_as_float(p << 16);          // element 2i (low u16)
    b = __uint_as_float(p & 0xFFFF0000u);  // element 2i+1 (high u16)
}
__device__ __forceinline__ u64 min_u64(u64 a, u64 b) { return a < b ? a : b; }

// ---------------------------------------------------------------------------
// Cast x / Wq / Wk / Wv (fp32) -> bf16, 8 elements/thread. grid.z selects.
// ---------------------------------------------------------------------------
__global__ __launch_bounds__(256) void cast_kernel(const float* __restrict__ x,
                                                   const float* __restrict__ wq,
                                                   const float* __restrict__ wk,
                                                   const float* __restrict__ wv,
                                                   bf16_t* __restrict__ xb,
                                                   bf16_t* __restrict__ wqb,
                                                   bf16_t* __restrict__ wkb,
                                                   bf16_t* __restrict__ wvb) {
    const int z = blockIdx.z;
    const float* src = (z == 0) ? x : (z == 1) ? wq : (z == 2) ? wk : wv;
    bf16_t* dst      = (z == 0) ? xb : (z == 1) ? wqb : (z == 2) ? wkb : wvb;
    const size_t cnt8 = (z == 0) ? (BSF / 8) : ((size_t)FDIM * FDIM / 8);
    size_t idx = (size_t)blockIdx.x * 256 + threadIdx.x;
    if (idx >= cnt8) return;
    const float4 a = ((const float4*)src)[idx * 2 + 0];
    const float4 b = ((const float4*)src)[idx * 2 + 1];
    uint4 o;
    o.x = (u32)f2bf(a.x) | ((u32)f2bf(a.y) << 16);
    o.y = (u32)f2bf(a.z) | ((u32)f2bf(a.w) << 16);
    o.z = (u32)f2bf(b.x) | ((u32)f2bf(b.y) << 16);
    o.w = (u32)f2bf(b.z) | ((u32)f2bf(b.w) << 16);
    ((uint4*)dst)[idx] = o;
}

// ---------------------------------------------------------------------------
// kNN: one block (256 thr = 4 waves) per FOUR queries. Staging: each thread
// computes 8 candidates' distances to all 4 queries (coords amortized in
// registers), sorts 8-lists, writes split u32/u16 LDS lists. Extraction:
// wave w extracts query q0+w (all 4 waves busy): 33 successive-unique-min
// rounds. Per round: lane-local u64 min of 4 heads (resolves intra-lane ties
// by idx), cross-lane min on 32-bit dist (6 shuffles), winner via
// ballot+ffs; rare cross-lane dist tie -> 6-shuffle idx min. Exact
// (dist,idx) stable-argsort order, self at rank 0 dropped — semantics
// identical to rounds 6-9 (all HW-validated).
// ---------------------------------------------------------------------------
__global__ __launch_bounds__(256) void knn_kernel(const float* __restrict__ coords,
                                                  u16* __restrict__ nn_out) {
    __shared__ u32 distd[4][2048];        // 32 KB  [query][pos*256+thread]
    __shared__ u16 idxs [4][2048];        // 16 KB
    const int blk = blockIdx.x;           // b*512 + qg   (qg = group of 4 queries)
    const int b   = blk >> 9;
    const int q0  = (blk & 511) * 4;
    const int t   = threadIdx.x;
    const int wid = t >> 6, lane = t & 63;

    const float* cb = coords + (size_t)b * SEQ * 3;

    // query coords (wave-uniform scalar loads)
    float qx[4], qy[4], qz[4];
#pragma unroll
    for (int qq = 0; qq < 4; ++qq) {
        qx[qq] = cb[(q0 + qq) * 3 + 0];
        qy[qq] = cb[(q0 + qq) * 3 + 1];
        qz[qq] = cb[(q0 + qq) * 3 + 2];
    }
    // candidate coords, 8 per thread, kept in registers across the 4 queries
    float cx[8], cy[8], cz[8];
#pragma unroll
    for (int i = 0; i < 8; ++i) {
        int c = i * 256 + t;
        cx[i] = cb[c * 3 + 0];
        cy[i] = cb[c * 3 + 1];
        cz[i] = cb[c * 3 + 2];
    }

#pragma unroll
    for (int qq = 0; qq < 4; ++qq) {
        u64 key[8];
#pragma unroll
        for (int i = 0; i < 8; ++i) {
            int c = i * 256 + t;
            float dx = __fsub_rn(cx[i], qx[qq]);
            float dy = __fsub_rn(cy[i], qy[qq]);
            float dz = __fsub_rn(cz[i], qz[qq]);
            // numpy order: (dx*dx + dy*dy) + dz*dz, no FMA, IEEE sqrt
            float d2 = __fadd_rn(__fadd_rn(__fmul_rn(dx, dx), __fmul_rn(dy, dy)),
                                 __fmul_rn(dz, dz));
            float dist = __fsqrt_rn(d2);
            key[i] = (((u64)__float_as_uint(dist)) << 32) | (u32)c;   // self included
        }
        // bitonic sort-8 ascending, fully unrolled
#pragma unroll
        for (int k = 2; k <= 8; k <<= 1) {
#pragma unroll
            for (int j = k >> 1; j > 0; j >>= 1) {
#pragma unroll
                for (int i = 0; i < 8; ++i) {
                    int ixj = i ^ j;
                    if (ixj > i) {
                        bool up = (i & k) == 0;
                        u64 a = key[i], c2 = key[ixj];
                        bool sw = up ? (a > c2) : (a < c2);
                        u64 lo = sw ? c2 : a;
                        u64 hi = sw ? a : c2;
                        key[i] = lo;
                        key[ixj] = hi;
                    }
                }
            }
        }
#pragma unroll
        for (int i = 0; i < 8; ++i) {
            distd[qq][i * 256 + t] = (u32)(key[i] >> 32);
            idxs [qq][i * 256 + t] = (u16)key[i];
        }
    }
    __syncthreads();

    // wave `wid` extracts query q0+wid; lane merges 4 lists of 8
    u64 h[4]; int p[4];
#pragma unroll
    for (int w = 0; w < 4; ++w) {
        int s = lane + 64 * w;
        h[w] = (((u64)distd[wid][s]) << 32) | idxs[wid][s];
        p[w] = 1;
    }

    u32 my = 0;
#pragma unroll 1
    for (int r = 0; r < KNN + 1; ++r) {          // rank 0 = self slot, dropped
        u64 lm = min_u64(min_u64(h[0], h[1]), min_u64(h[2], h[3]));
        u32 d = (u32)(lm >> 32);
        u32 m = d;                               // 6-step u32 min reduce
        m = min(m, (u32)__shfl_xor((int)m, 1, 64));
        m = min(m, (u32)__shfl_xor((int)m, 2, 64));
        m = min(m, (u32)__shfl_xor((int)m, 4, 64));
        m = min(m, (u32)__shfl_xor((int)m, 8, 64));
        m = min(m, (u32)__shfl_xor((int)m, 16, 64));
        m = min(m, (u32)__shfl_xor((int)m, 32, 64));
        u64 mask = __ballot(d == m);
        u32 win_idx;
        if (__popcll(mask) == 1) {               // common case: unique dist
            int winner = __ffsll((long long)mask) - 1;
            win_idx = (u32)__shfl((int)(u32)lm, winner, 64);   // low 32 = idx
        } else {                                 // rare: dist tie -> min idx
            u32 ti = (d == m) ? (u32)lm : 0xFFFFFFFFu;
            ti = min(ti, (u32)__shfl_xor((int)ti, 1, 64));
            ti = min(ti, (u32)__shfl_xor((int)ti, 2, 64));
            ti = min(ti, (u32)__shfl_xor((int)ti, 4, 64));
            ti = min(ti, (u32)__shfl_xor((int)ti, 8, 64));
            ti = min(ti, (u32)__shfl_xor((int)ti, 16, 64));
            ti = min(ti, (u32)__shfl_xor((int)ti, 32, 64));
            win_idx = ti;
        }
        if (r == lane + 1) my = win_idx;         // lane j captures rank j+1
        u64 mfull = (((u64)m) << 32) | win_idx;
#pragma unroll
        for (int w = 0; w < 4; ++w) {
            if (h[w] == mfull) {                 // unique winner refills
                int s = lane + 64 * w;
                h[w] = (p[w] < 8) ? ((((u64)distd[wid][p[w] * 256 + s]) << 32)
                                     | idxs[wid][p[w] * 256 + s])
                                  : ~0ull;
                ++p[w];
            }
        }
    }
    if (lane < KNN)
        nn_out[((size_t)(b << 11) + q0 + wid) * KNN + lane] = (u16)(my & 0x7FF);
}

// ---------------------------------------------------------------------------
// LDS-tiled MFMA GEMM (m93 structure): out[m,n] = sum_k A[m,k]*W[n,k].
// 128x128 block tile, BK=32, 256 thr = 4 waves (2x2), 64x64 wave tile,
// 4x4 grid of 16x16x32 MFMAs, fp32 acc. VGPR-staged LDS (16 KB).
// z=0 -> q (fp32 to d_out); z=1,2 -> k,v (bf16 to ws).
// ---------------------------------------------------------------------------
__global__ __launch_bounds__(256) void gemm_mfma(const bf16_t* __restrict__ xb,
                                                 const bf16_t* __restrict__ wqb,
                                                 const bf16_t* __restrict__ wkb,
                                                 const bf16_t* __restrict__ wvb,
                                                 float* __restrict__ qout,
                                                 bf16_t* __restrict__ kvout) {
    __shared__ __align__(16) bf16_t As[128 * 32];
    __shared__ __align__(16) bf16_t Bs[128 * 32];
    const int z = blockIdx.z;
    const bf16_t* W = (z == 0) ? wqb : (z == 1) ? wkb : wvb;
    const int tid  = threadIdx.x;
    const int wid  = tid >> 6, lane = tid & 63;
    const int m16  = lane & 15, quad = lane >> 4;
    const int wm   = (wid & 1) * 64;
    const int wn   = (wid >> 1) * 64;
    const int m0   = blockIdx.y * 128;
    const int n0   = blockIdx.x * 128;

    const int sr = tid >> 2, sc = (tid & 3) * 8;
    const bf16_t* agp = xb + (size_t)(m0 + sr) * FDIM + sc;
    const bf16_t* bgp = W  + (size_t)(n0 + sr) * FDIM + sc;

    f32x4 acc[4][4];
#pragma unroll
    for (int i = 0; i < 4; ++i)
#pragma unroll
        for (int j = 0; j < 4; ++j) acc[i][j] = (f32x4){0.f, 0.f, 0.f, 0.f};

#pragma unroll 1
    for (int k0 = 0; k0 < FDIM; k0 += 32) {
        uint4 a0 = *(const uint4*)(agp + k0);
        uint4 a1 = *(const uint4*)(agp + (size_t)64 * FDIM + k0);
        uint4 b0 = *(const uint4*)(bgp + k0);
        uint4 b1 = *(const uint4*)(bgp + (size_t)64 * FDIM + k0);
        __syncthreads();
        *(uint4*)(As + sr * 32 + sc)        = a0;
        *(uint4*)(As + (sr + 64) * 32 + sc) = a1;
        *(uint4*)(Bs + sr * 32 + sc)        = b0;
        *(uint4*)(Bs + (sr + 64) * 32 + sc) = b1;
        __syncthreads();

        short8 af[4], bfr[4];
#pragma unroll
        for (int i = 0; i < 4; ++i)
            af[i] = *(const short8*)(As + (wm + i * 16 + m16) * 32 + quad * 8);
#pragma unroll
        for (int j = 0; j < 4; ++j)
            bfr[j] = *(const short8*)(Bs + (wn + j * 16 + m16) * 32 + quad * 8);
#pragma unroll
        for (int i = 0; i < 4; ++i)
#pragma unroll
            for (int j = 0; j < 4; ++j)
                acc[i][j] = __builtin_amdgcn_mfma_f32_16x16x32_bf16(af[i], bfr[j],
                                                                    acc[i][j], 0, 0, 0);
    }

    if (z == 0) {
#pragma unroll
        for (int i = 0; i < 4; ++i) {
            const int rowb = m0 + wm + i * 16 + quad * 4;
#pragma unroll
            for (int r = 0; r < 4; ++r) {
                float* orow = qout + (size_t)(rowb + r) * FDIM + n0 + wn + m16;
                orow[ 0] = acc[i][0][r]; orow[16] = acc[i][1][r];
                orow[32] = acc[i][2][r]; orow[48] = acc[i][3][r];
            }
        }
    } else {
        bf16_t* base = kvout + (size_t)(z - 1) * BSF;
#pragma unroll
        for (int i = 0; i < 4; ++i) {
            const int rowb = m0 + wm + i * 16 + quad * 4;
#pragma unroll
            for (int r = 0; r < 4; ++r) {
                bf16_t* orow = base + (size_t)(rowb + r) * FDIM + n0 + wn + m16;
                orow[ 0] = f2bf(acc[i][0][r]); orow[16] = f2bf(acc[i][1][r]);
                orow[32] = f2bf(acc[i][2][r]); orow[48] = f2bf(acc[i][3][r]);
            }
        }
    }
}

// ---------------------------------------------------------------------------
// Attention, ALL batches: block per (b,q), 512 thr = 8 waves, wave per head.
// kv bf16 = [k_all | v_all] in ws. q read fp32 from d_out (own row), then
// overwritten with the result.
// ---------------------------------------------------------------------------
__global__ __launch_bounds__(512) void attn_kernel(const bf16_t* __restrict__ kv,
                                                   const u16* __restrict__ nn,
                                                   float* __restrict__ out) {
    __shared__ float qs[FDIM];
    __shared__ int   sidx[KNN];
    __shared__ float wls[NHEAD][KNN];
    const int blk = blockIdx.x;            // b*SEQ + q
    const int b   = blk >> 11;
    const int tid = threadIdx.x;
    const int h = tid >> 6, lane = tid & 63;

    qs[tid] = out[(size_t)blk * FDIM + tid];                  // own q row
    if (tid < KNN) sidx[tid] = (int)nn[(size_t)blk * KNN + tid] & (SEQ - 1);
    __syncthreads();

    const int j = lane & 31, half = lane >> 5;
    const bf16_t* kreg = kv + ((size_t)((b << 11) + sidx[j])) * FDIM + h * HDIM + half * 32;
    const float* qp = &qs[h * HDIM + half * 32];
    float acc = 0.f;
#pragma unroll
    for (int d = 0; d < 32; d += 8) {
        uint4 kvv = *(const uint4*)(kreg + d);   // 8 bf16
        float f0, f1, f2, f3, f4, f5, f6, f7;
        bf2x2(kvv.x, f0, f1); bf2x2(kvv.y, f2, f3);
        bf2x2(kvv.z, f4, f5); bf2x2(kvv.w, f6, f7);
        acc += qp[d + 0] * f0 + qp[d + 1] * f1 + qp[d + 2] * f2 + qp[d + 3] * f3
             + qp[d + 4] * f4 + qp[d + 5] * f5 + qp[d + 6] * f6 + qp[d + 7] * f7;
    }
    acc += __shfl_xor(acc, 32, 64);
    float s = acc * 0.125f;                 // 1/sqrt(64)
    float m = s;
    m = fmaxf(m, __shfl_xor(m, 1, 64));
    m = fmaxf(m, __shfl_xor(m, 2, 64));
    m = fmaxf(m, __shfl_xor(m, 4, 64));
    m = fmaxf(m, __shfl_xor(m, 8, 64));
    m = fmaxf(m, __shfl_xor(m, 16, 64));
    float e = __expf(s - m);
    float sum = e;
    sum += __shfl_xor(sum, 1, 64);
    sum += __shfl_xor(sum, 2, 64);
    sum += __shfl_xor(sum, 4, 64);
    sum += __shfl_xor(sum, 8, 64);
    sum += __shfl_xor(sum, 16, 64);
    float w = e / sum;
    if (half == 0) wls[h][j] = w;
    __syncthreads();

    const bf16_t* vb = kv + BSF + ((size_t)(b << 11)) * FDIM + h * HDIM + lane;
    float o = 0.f;
#pragma unroll 4
    for (int j2 = 0; j2 < KNN; ++j2) {
        o += wls[h][j2] * bf2f(vb[(size_t)sidx[j2] * FDIM]);
    }
    out[(size_t)blk * FDIM + h * HDIM + lane] = o;
}

// ---------------------------------------------------------------------------
// metric = mean_s(k) = (mean_s x) @ Wk^T  (linearity), fp32 from raw inputs
// ---------------------------------------------------------------------------
__global__ __launch_bounds__(256) void xbar_kernel(const float* __restrict__ x,
                                                   float* __restrict__ xbar) {
    const int b = blockIdx.x, chunk = blockIdx.y;   // 32 chunks of 64 rows
    const int tid = threadIdx.x;
    const float* xp = x + (size_t)b * SF + (size_t)chunk * 64 * FDIM;
    float s0 = 0.f, s1 = 0.f;
    for (int r = 0; r < 64; ++r) {
        s0 += xp[(size_t)r * FDIM + tid];
        s1 += xp[(size_t)r * FDIM + tid + 256];
    }
    atomicAdd(&xbar[b * FDIM + tid],       s0 * (1.f / 2048.f));
    atomicAdd(&xbar[b * FDIM + tid + 256], s1 * (1.f / 2048.f));
}

__global__ __launch_bounds__(256) void metric_kernel(const float* __restrict__ xbar,
                                                     const float* __restrict__ Wk,
                                                     float* __restrict__ metric) {
    const int o = blockIdx.x * 256 + threadIdx.x;   // 2048 outputs
    const int b = o >> 9, f = o & 511;
    const float* xb = xbar + b * FDIM;
    const float* wr = Wk + (size_t)f * FDIM;
    float acc = 0.f;
#pragma unroll 4
    for (int kk = 0; kk < FDIM; kk += 4) {
        float4 wv = *(const float4*)(wr + kk);
        acc += xb[kk + 0] * wv.x + xb[kk + 1] * wv.y
             + xb[kk + 2] * wv.z + xb[kk + 3] * wv.w;
    }
    metric[o] = acc;
}

// ---------------------------------------------------------------------------
extern "C" void kernel_launch(void* const* d_in, const int* in_sizes, int n_in,
                              void* d_out, int out_size, void* d_ws, size_t ws_size,
                              hipStream_t stream) {
    const float* x      = (const float*)d_in[0];
    const float* coords = (const float*)d_in[1];
    const float* Wq     = (const float*)d_in[2];
    const float* Wk     = (const float*)d_in[3];
    const float* Wv     = (const float*)d_in[4];
    float* out    = (float*)d_out;
    float* metric = out + BSF;

    // ws layout (26.0 MiB):
    //   xb bf16 BSF (8 MiB) | wqb/wkb/wvb bf16 (1.5 MiB) | kv bf16 2*BSF (16 MiB)
    //   | nn u16 (0.5 MiB) | xbar f32 (8 KiB)
    char* p = (char*)d_ws;
    bf16_t* xb   = (bf16_t*)p;                       p += BSF * sizeof(bf16_t);
    bf16_t* wqb  = (bf16_t*)p;                       p += (size_t)FDIM * FDIM * sizeof(bf16_t);
    bf16_t* wkb  = (bf16_t*)p;                       p += (size_t)FDIM * FDIM * sizeof(bf16_t);
    bf16_t* wvb  = (bf16_t*)p;                       p += (size_t)FDIM * FDIM * sizeof(bf16_t);
    bf16_t* kv   = (bf16_t*)p;                       p += 2 * BSF * sizeof(bf16_t);
    u16*    nn   = (u16*)p;                          p += (size_t)BATCH * SEQ * KNN * sizeof(u16);
    float*  xbar = (float*)p;

    cast_kernel<<<dim3(BSF / 8 / 256, 1, 4), 256, 0, stream>>>(x, Wq, Wk, Wv,
                                                               xb, wqb, wkb, wvb);
    knn_kernel<<<(BATCH * SEQ) / 4, 256, 0, stream>>>(coords, nn);

    // q -> d_out (fp32), k/v -> ws (bf16); one dispatch, 128x128 tiles
    gemm_mfma<<<dim3(FDIM / 128, (BATCH * SEQ) / 128, 3), 256, 0, stream>>>(
        xb, wqb, wkb, wvb, out, kv);

    hipMemsetAsync(xbar, 0, BATCH * FDIM * sizeof(float), stream);
    xbar_kernel<<<dim3(BATCH, 32), 256, 0, stream>>>(x, xbar);
    metric_kernel<<<(BATCH * NHEAD * HDIM) / 256, 256, 0, stream>>>(xbar, Wk, metric);

    attn_kernel<<<BATCH * SEQ, 512, 0, stream>>>(kv, nn, out);
}

// Round 11
// 249.823 us; speedup vs baseline: 1.0684x; 1.0030x over previous
//
#include <hip/hip_runtime.h>
#include <stdint.h>

#define BATCH 4
#define SEQ   2048
#define FDIM  512
#define NHEAD 8
#define HDIM  64
#define KNN   32

typedef unsigned int u32;
typedef unsigned long long u64;
typedef unsigned short u16;
typedef unsigned short bf16_t;

typedef __attribute__((ext_vector_type(8))) short short8;   // 8 bf16 = 4 VGPRs
typedef __attribute__((ext_vector_type(4))) float f32x4;

#define SF  ((size_t)SEQ * FDIM)            // 1,048,576 per-batch elements
#define BSF ((size_t)BATCH * SF)            // 4,194,304

__device__ __forceinline__ bf16_t f2bf(float f) {
    u32 x = __float_as_uint(f);
    return (bf16_t)((x + 0x7FFFu + ((x >> 16) & 1u)) >> 16);   // RNE
}
__device__ __forceinline__ float bf2f(bf16_t u) { return __uint_as_float(((u32)u) << 16); }
__device__ __forceinline__ void bf2x2(u32 p, float& a, float& b) {
    a = __uint_as_float(p << 16);          // element 2i (low u16)
    b = __uint_as_float(p & 0xFFFF0000u);  // element 2i+1 (high u16)
}
__device__ __forceinline__ u64 min_u64(u64 a, u64 b) { return a < b ? a : b; }

// ---------------------------------------------------------------------------
// Cast x / Wq / Wk / Wv (fp32) -> bf16, 8 elements/thread. grid.z selects.
// ---------------------------------------------------------------------------
__global__ __launch_bounds__(256) void cast_kernel(const float* __restrict__ x,
                                                   const float* __restrict__ wq,
                                                   const float* __restrict__ wk,
                                                   const float* __restrict__ wv,
                                                   bf16_t* __restrict__ xb,
                                                   bf16_t* __restrict__ wqb,
                                                   bf16_t* __restrict__ wkb,
                                                   bf16_t* __restrict__ wvb) {
    const int z = blockIdx.z;
    const float* src = (z == 0) ? x : (z == 1) ? wq : (z == 2) ? wk : wv;
    bf16_t* dst      = (z == 0) ? xb : (z == 1) ? wqb : (z == 2) ? wkb : wvb;
    const size_t cnt8 = (z == 0) ? (BSF / 8) : ((size_t)FDIM * FDIM / 8);
    size_t idx = (size_t)blockIdx.x * 256 + threadIdx.x;
    if (idx >= cnt8) return;
    const float4 a = ((const float4*)src)[idx * 2 + 0];
    const float4 b = ((const float4*)src)[idx * 2 + 1];
    uint4 o;
    o.x = (u32)f2bf(a.x) | ((u32)f2bf(a.y) << 16);
    o.y = (u32)f2bf(a.z) | ((u32)f2bf(a.w) << 16);
    o.z = (u32)f2bf(b.x) | ((u32)f2bf(b.y) << 16);
    o.w = (u32)f2bf(b.z) | ((u32)f2bf(b.w) << 16);
    ((uint4*)dst)[idx] = o;
}

// ---------------------------------------------------------------------------
// kNN: one block (256 thr = 4 waves) per FOUR queries (round-10 structure,
// HW-validated). Stable-argsort-exact semantics, self at rank 0 dropped.
// ---------------------------------------------------------------------------
__global__ __launch_bounds__(256) void knn_kernel(const float* __restrict__ coords,
                                                  u16* __restrict__ nn_out) {
    __shared__ u32 distd[4][2048];        // 32 KB  [query][pos*256+thread]
    __shared__ u16 idxs [4][2048];        // 16 KB
    const int blk = blockIdx.x;           // b*512 + qg
    const int b   = blk >> 9;
    const int q0  = (blk & 511) * 4;
    const int t   = threadIdx.x;
    const int wid = t >> 6, lane = t & 63;

    const float* cb = coords + (size_t)b * SEQ * 3;

    float qx[4], qy[4], qz[4];
#pragma unroll
    for (int qq = 0; qq < 4; ++qq) {
        qx[qq] = cb[(q0 + qq) * 3 + 0];
        qy[qq] = cb[(q0 + qq) * 3 + 1];
        qz[qq] = cb[(q0 + qq) * 3 + 2];
    }
    float cx[8], cy[8], cz[8];
#pragma unroll
    for (int i = 0; i < 8; ++i) {
        int c = i * 256 + t;
        cx[i] = cb[c * 3 + 0];
        cy[i] = cb[c * 3 + 1];
        cz[i] = cb[c * 3 + 2];
    }

#pragma unroll
    for (int qq = 0; qq < 4; ++qq) {
        u64 key[8];
#pragma unroll
        for (int i = 0; i < 8; ++i) {
            int c = i * 256 + t;
            float dx = __fsub_rn(cx[i], qx[qq]);
            float dy = __fsub_rn(cy[i], qy[qq]);
            float dz = __fsub_rn(cz[i], qz[qq]);
            // numpy order: (dx*dx + dy*dy) + dz*dz, no FMA, IEEE sqrt
            float d2 = __fadd_rn(__fadd_rn(__fmul_rn(dx, dx), __fmul_rn(dy, dy)),
                                 __fmul_rn(dz, dz));
            float dist = __fsqrt_rn(d2);
            key[i] = (((u64)__float_as_uint(dist)) << 32) | (u32)c;   // self included
        }
#pragma unroll
        for (int k = 2; k <= 8; k <<= 1) {
#pragma unroll
            for (int j = k >> 1; j > 0; j >>= 1) {
#pragma unroll
                for (int i = 0; i < 8; ++i) {
                    int ixj = i ^ j;
                    if (ixj > i) {
                        bool up = (i & k) == 0;
                        u64 a = key[i], c2 = key[ixj];
                        bool sw = up ? (a > c2) : (a < c2);
                        u64 lo = sw ? c2 : a;
                        u64 hi = sw ? a : c2;
                        key[i] = lo;
                        key[ixj] = hi;
                    }
                }
            }
        }
#pragma unroll
        for (int i = 0; i < 8; ++i) {
            distd[qq][i * 256 + t] = (u32)(key[i] >> 32);
            idxs [qq][i * 256 + t] = (u16)key[i];
        }
    }
    __syncthreads();

    u64 h[4]; int p[4];
#pragma unroll
    for (int w = 0; w < 4; ++w) {
        int s = lane + 64 * w;
        h[w] = (((u64)distd[wid][s]) << 32) | idxs[wid][s];
        p[w] = 1;
    }

    u32 my = 0;
#pragma unroll 1
    for (int r = 0; r < KNN + 1; ++r) {          // rank 0 = self slot, dropped
        u64 lm = min_u64(min_u64(h[0], h[1]), min_u64(h[2], h[3]));
        u32 d = (u32)(lm >> 32);
        u32 m = d;
        m = min(m, (u32)__shfl_xor((int)m, 1, 64));
        m = min(m, (u32)__shfl_xor((int)m, 2, 64));
        m = min(m, (u32)__shfl_xor((int)m, 4, 64));
        m = min(m, (u32)__shfl_xor((int)m, 8, 64));
        m = min(m, (u32)__shfl_xor((int)m, 16, 64));
        m = min(m, (u32)__shfl_xor((int)m, 32, 64));
        u64 mask = __ballot(d == m);
        u32 win_idx;
        if (__popcll(mask) == 1) {               // common case: unique dist
            int winner = __ffsll((long long)mask) - 1;
            win_idx = (u32)__shfl((int)(u32)lm, winner, 64);
        } else {                                 // rare: dist tie -> min idx
            u32 ti = (d == m) ? (u32)lm : 0xFFFFFFFFu;
            ti = min(ti, (u32)__shfl_xor((int)ti, 1, 64));
            ti = min(ti, (u32)__shfl_xor((int)ti, 2, 64));
            ti = min(ti, (u32)__shfl_xor((int)ti, 4, 64));
            ti = min(ti, (u32)__shfl_xor((int)ti, 8, 64));
            ti = min(ti, (u32)__shfl_xor((int)ti, 16, 64));
            ti = min(ti, (u32)__shfl_xor((int)ti, 32, 64));
            win_idx = ti;
        }
        if (r == lane + 1) my = win_idx;
        u64 mfull = (((u64)m) << 32) | win_idx;
#pragma unroll
        for (int w = 0; w < 4; ++w) {
            if (h[w] == mfull) {
                int s = lane + 64 * w;
                h[w] = (p[w] < 8) ? ((((u64)distd[wid][p[w] * 256 + s]) << 32)
                                     | idxs[wid][p[w] * 256 + s])
                                  : ~0ull;
                ++p[w];
            }
        }
    }
    if (lane < KNN)
        nn_out[((size_t)(b << 11) + q0 + wid) * KNN + lane] = (u16)(my & 0x7FF);
}

// ---------------------------------------------------------------------------
// LDS-tiled MFMA GEMM (m93 structure): out[m,n] = sum_k A[m,k]*W[n,k].
// 128x128 block tile, BK=32, 256 thr = 4 waves (2x2), 64x64 wave tile.
// z=0 -> q (fp32 to d_out); z=1,2 -> k,v (bf16 to ws).
// ---------------------------------------------------------------------------
__global__ __launch_bounds__(256) void gemm_mfma(const bf16_t* __restrict__ xb,
                                                 const bf16_t* __restrict__ wqb,
                                                 const bf16_t* __restrict__ wkb,
                                                 const bf16_t* __restrict__ wvb,
                                                 float* __restrict__ qout,
                                                 bf16_t* __restrict__ kvout) {
    __shared__ __align__(16) bf16_t As[128 * 32];
    __shared__ __align__(16) bf16_t Bs[128 * 32];
    const int z = blockIdx.z;
    const bf16_t* W = (z == 0) ? wqb : (z == 1) ? wkb : wvb;
    const int tid  = threadIdx.x;
    const int wid  = tid >> 6, lane = tid & 63;
    const int m16  = lane & 15, quad = lane >> 4;
    const int wm   = (wid & 1) * 64;
    const int wn   = (wid >> 1) * 64;
    const int m0   = blockIdx.y * 128;
    const int n0   = blockIdx.x * 128;

    const int sr = tid >> 2, sc = (tid & 3) * 8;
    const bf16_t* agp = xb + (size_t)(m0 + sr) * FDIM + sc;
    const bf16_t* bgp = W  + (size_t)(n0 + sr) * FDIM + sc;

    f32x4 acc[4][4];
#pragma unroll
    for (int i = 0; i < 4; ++i)
#pragma unroll
        for (int j = 0; j < 4; ++j) acc[i][j] = (f32x4){0.f, 0.f, 0.f, 0.f};

#pragma unroll 1
    for (int k0 = 0; k0 < FDIM; k0 += 32) {
        uint4 a0 = *(const uint4*)(agp + k0);
        uint4 a1 = *(const uint4*)(agp + (size_t)64 * FDIM + k0);
        uint4 b0 = *(const uint4*)(bgp + k0);
        uint4 b1 = *(const uint4*)(bgp + (size_t)64 * FDIM + k0);
        __syncthreads();
        *(uint4*)(As + sr * 32 + sc)        = a0;
        *(uint4*)(As + (sr + 64) * 32 + sc) = a1;
        *(uint4*)(Bs + sr * 32 + sc)        = b0;
        *(uint4*)(Bs + (sr + 64) * 32 + sc) = b1;
        __syncthreads();

        short8 af[4], bfr[4];
#pragma unroll
        for (int i = 0; i < 4; ++i)
            af[i] = *(const short8*)(As + (wm + i * 16 + m16) * 32 + quad * 8);
#pragma unroll
        for (int j = 0; j < 4; ++j)
            bfr[j] = *(const short8*)(Bs + (wn + j * 16 + m16) * 32 + quad * 8);
#pragma unroll
        for (int i = 0; i < 4; ++i)
#pragma unroll
            for (int j = 0; j < 4; ++j)
                acc[i][j] = __builtin_amdgcn_mfma_f32_16x16x32_bf16(af[i], bfr[j],
                                                                    acc[i][j], 0, 0, 0);
    }

    if (z == 0) {
#pragma unroll
        for (int i = 0; i < 4; ++i) {
            const int rowb = m0 + wm + i * 16 + quad * 4;
#pragma unroll
            for (int r = 0; r < 4; ++r) {
                float* orow = qout + (size_t)(rowb + r) * FDIM + n0 + wn + m16;
                orow[ 0] = acc[i][0][r]; orow[16] = acc[i][1][r];
                orow[32] = acc[i][2][r]; orow[48] = acc[i][3][r];
            }
        }
    } else {
        bf16_t* base = kvout + (size_t)(z - 1) * BSF;
#pragma unroll
        for (int i = 0; i < 4; ++i) {
            const int rowb = m0 + wm + i * 16 + quad * 4;
#pragma unroll
            for (int r = 0; r < 4; ++r) {
                bf16_t* orow = base + (size_t)(rowb + r) * FDIM + n0 + wn + m16;
                orow[ 0] = f2bf(acc[i][0][r]); orow[16] = f2bf(acc[i][1][r]);
                orow[32] = f2bf(acc[i][2][r]); orow[48] = f2bf(acc[i][3][r]);
            }
        }
    }
}

// ---------------------------------------------------------------------------
// Attention, ALL batches: block per (b,q), 512 thr = 8 waves, wave per head.
// XCD-aware swizzle: dispatch index i -> XCD ~ i&7 (round-robin heuristic);
// map batch b to XCD pair {2b,2b+1} so each pair's L2 (8 MiB) holds that
// batch's 4 MB kv -> HBM fetch of kv ~once instead of ~5x. Correctness is
// mapping-independent (bijective remap only).
// ---------------------------------------------------------------------------
__global__ __launch_bounds__(512) void attn_kernel(const bf16_t* __restrict__ kv,
                                                   const u16* __restrict__ nn,
                                                   float* __restrict__ out) {
    __shared__ float qs[FDIM];
    __shared__ int   sidx[KNN];
    __shared__ float wls[NHEAD][KNN];
    const int i   = blockIdx.x;
    const int b   = (i & 7) >> 1;                         // XCD pair -> batch
    const int qi  = ((i >> 3) << 1) | (i & 1);            // 0..2047, bijective
    const int blk = (b << 11) | qi;
    const int tid = threadIdx.x;
    const int h = tid >> 6, lane = tid & 63;

    qs[tid] = out[(size_t)blk * FDIM + tid];                  // own q row
    if (tid < KNN) sidx[tid] = (int)nn[(size_t)blk * KNN + tid] & (SEQ - 1);
    __syncthreads();

    const int j = lane & 31, half = lane >> 5;
    const bf16_t* kreg = kv + ((size_t)((b << 11) + sidx[j])) * FDIM + h * HDIM + half * 32;
    const float* qp = &qs[h * HDIM + half * 32];
    float acc = 0.f;
#pragma unroll
    for (int d = 0; d < 32; d += 8) {
        uint4 kvv = *(const uint4*)(kreg + d);   // 8 bf16
        float f0, f1, f2, f3, f4, f5, f6, f7;
        bf2x2(kvv.x, f0, f1); bf2x2(kvv.y, f2, f3);
        bf2x2(kvv.z, f4, f5); bf2x2(kvv.w, f6, f7);
        acc += qp[d + 0] * f0 + qp[d + 1] * f1 + qp[d + 2] * f2 + qp[d + 3] * f3
             + qp[d + 4] * f4 + qp[d + 5] * f5 + qp[d + 6] * f6 + qp[d + 7] * f7;
    }
    acc += __shfl_xor(acc, 32, 64);
    float s = acc * 0.125f;                 // 1/sqrt(64)
    float m = s;
    m = fmaxf(m, __shfl_xor(m, 1, 64));
    m = fmaxf(m, __shfl_xor(m, 2, 64));
    m = fmaxf(m, __shfl_xor(m, 4, 64));
    m = fmaxf(m, __shfl_xor(m, 8, 64));
    m = fmaxf(m, __shfl_xor(m, 16, 64));
    float e = __expf(s - m);
    float sum = e;
    sum += __shfl_xor(sum, 1, 64);
    sum += __shfl_xor(sum, 2, 64);
    sum += __shfl_xor(sum, 4, 64);
    sum += __shfl_xor(sum, 8, 64);
    sum += __shfl_xor(sum, 16, 64);
    float w = e / sum;
    if (half == 0) wls[h][j] = w;
    __syncthreads();

    const bf16_t* vb = kv + BSF + ((size_t)(b << 11)) * FDIM + h * HDIM + lane;
    float o = 0.f;
#pragma unroll 4
    for (int j2 = 0; j2 < KNN; ++j2) {
        o += wls[h][j2] * bf2f(vb[(size_t)sidx[j2] * FDIM]);
    }
    out[(size_t)blk * FDIM + h * HDIM + lane] = o;
}

// ---------------------------------------------------------------------------
// metric = mean_s(k) = (mean_s x) @ Wk^T  (linearity), fp32 from raw inputs
// ---------------------------------------------------------------------------
__global__ __launch_bounds__(256) void xbar_kernel(const float* __restrict__ x,
                                                   float* __restrict__ xbar) {
    const int b = blockIdx.x, chunk = blockIdx.y;   // 32 chunks of 64 rows
    const int tid = threadIdx.x;
    const float* xp = x + (size_t)b * SF + (size_t)chunk * 64 * FDIM;
    float s0 = 0.f, s1 = 0.f;
    for (int r = 0; r < 64; ++r) {
        s0 += xp[(size_t)r * FDIM + tid];
        s1 += xp[(size_t)r * FDIM + tid + 256];
    }
    atomicAdd(&xbar[b * FDIM + tid],       s0 * (1.f / 2048.f));
    atomicAdd(&xbar[b * FDIM + tid + 256], s1 * (1.f / 2048.f));
}

__global__ __launch_bounds__(256) void metric_kernel(const float* __restrict__ xbar,
                                                     const float* __restrict__ Wk,
                                                     float* __restrict__ metric) {
    const int o = blockIdx.x * 256 + threadIdx.x;   // 2048 outputs
    const int b = o >> 9, f = o & 511;
    const float* xb = xbar + b * FDIM;
    const float* wr = Wk + (size_t)f * FDIM;
    float acc = 0.f;
#pragma unroll 4
    for (int kk = 0; kk < FDIM; kk += 4) {
        float4 wv = *(const float4*)(wr + kk);
        acc += xb[kk + 0] * wv.x + xb[kk + 1] * wv.y
             + xb[kk + 2] * wv.z + xb[kk + 3] * wv.w;
    }
    metric[o] = acc;
}

// ---------------------------------------------------------------------------
extern "C" void kernel_launch(void* const* d_in, const int* in_sizes, int n_in,
                              void* d_out, int out_size, void* d_ws, size_t ws_size,
                              hipStream_t stream) {
    const float* x      = (const float*)d_in[0];
    const float* coords = (const float*)d_in[1];
    const float* Wq     = (const float*)d_in[2];
    const float* Wk     = (const float*)d_in[3];
    const float* Wv     = (const float*)d_in[4];
    float* out    = (float*)d_out;
    float* metric = out + BSF;

    // ws layout (26.0 MiB):
    //   xb bf16 BSF (8 MiB) | wqb/wkb/wvb bf16 (1.5 MiB) | kv bf16 2*BSF (16 MiB)
    //   | nn u16 (0.5 MiB) | xbar f32 (8 KiB)
    char* p = (char*)d_ws;
    bf16_t* xb   = (bf16_t*)p;                       p += BSF * sizeof(bf16_t);
    bf16_t* wqb  = (bf16_t*)p;                       p += (size_t)FDIM * FDIM * sizeof(bf16_t);
    bf16_t* wkb  = (bf16_t*)p;                       p += (size_t)FDIM * FDIM * sizeof(bf16_t);
    bf16_t* wvb  = (bf16_t*)p;                       p += (size_t)FDIM * FDIM * sizeof(bf16_t);
    bf16_t* kv   = (bf16_t*)p;                       p += 2 * BSF * sizeof(bf16_t);
    u16*    nn   = (u16*)p;                          p += (size_t)BATCH * SEQ * KNN * sizeof(u16);
    float*  xbar = (float*)p;

    cast_kernel<<<dim3(BSF / 8 / 256, 1, 4), 256, 0, stream>>>(x, Wq, Wk, Wv,
                                                               xb, wqb, wkb, wvb);
    knn_kernel<<<(BATCH * SEQ) / 4, 256, 0, stream>>>(coords, nn);

    // q -> d_out (fp32), k/v -> ws (bf16); one dispatch, 128x128 tiles
    gemm_mfma<<<dim3(FDIM / 128, (BATCH * SEQ) / 128, 3), 256, 0, stream>>>(
        xb, wqb, wkb, wvb, out, kv);

    hipMemsetAsync(xbar, 0, BATCH * FDIM * sizeof(float), stream);
    xbar_kernel<<<dim3(BATCH, 32), 256, 0, stream>>>(x, xbar);
    metric_kernel<<<(BATCH * NHEAD * HDIM) / 256, 256, 0, stream>>>(xbar, Wk, metric);

    attn_kernel<<<BATCH * SEQ, 512, 0, stream>>>(kv, nn, out);
}

// Round 12
// 243.043 us; speedup vs baseline: 1.0982x; 1.0279x over previous
//
#include <hip/hip_runtime.h>
#include <stdint.h>

#define BATCH 4
#define SEQ   2048
#define FDIM  512
#define NHEAD 8
#define HDIM  64
#define KNN   32

typedef unsigned int u32;
typedef unsigned long long u64;
typedef unsigned short u16;
typedef unsigned short bf16_t;

typedef __attribute__((ext_vector_type(8))) short short8;   // 8 bf16 = 4 VGPRs
typedef __attribute__((ext_vector_type(4))) float f32x4;

#define SF  ((size_t)SEQ * FDIM)            // 1,048,576 per-batch elements
#define BSF ((size_t)BATCH * SF)            // 4,194,304

__device__ __forceinline__ bf16_t f2bf(float f) {
    u32 x = __float_as_uint(f);
    return (bf16_t)((x + 0x7FFFu + ((x >> 16) & 1u)) >> 16);   // RNE
}
__device__ __forceinline__ float bf2f(bf16_t u) { return __uint_as_float(((u32)u) << 16); }
__device__ __forceinline__ void bf2x2(u32 p, float& a, float& b) {
    a = __uint_as_float(p << 16);          // element 2i (low u16)
    b = __uint_as_float(p & 0xFFFF0000u);  // element 2i+1 (high u16)
}
__device__ __forceinline__ u64 min_u64(u64 a, u64 b) { return a < b ? a : b; }

// ---------------------------------------------------------------------------
// Cast x / Wq / Wk / Wv (fp32) -> bf16, 8 elements/thread. grid.z selects.
// ---------------------------------------------------------------------------
__global__ __launch_bounds__(256) void cast_kernel(const float* __restrict__ x,
                                                   const float* __restrict__ wq,
                                                   const float* __restrict__ wk,
                                                   const float* __restrict__ wv,
                                                   bf16_t* __restrict__ xb,
                                                   bf16_t* __restrict__ wqb,
                                                   bf16_t* __restrict__ wkb,
                                                   bf16_t* __restrict__ wvb) {
    const int z = blockIdx.z;
    const float* src = (z == 0) ? x : (z == 1) ? wq : (z == 2) ? wk : wv;
    bf16_t* dst      = (z == 0) ? xb : (z == 1) ? wqb : (z == 2) ? wkb : wvb;
    const size_t cnt8 = (z == 0) ? (BSF / 8) : ((size_t)FDIM * FDIM / 8);
    size_t idx = (size_t)blockIdx.x * 256 + threadIdx.x;
    if (idx >= cnt8) return;
    const float4 a = ((const float4*)src)[idx * 2 + 0];
    const float4 b = ((const float4*)src)[idx * 2 + 1];
    uint4 o;
    o.x = (u32)f2bf(a.x) | ((u32)f2bf(a.y) << 16);
    o.y = (u32)f2bf(a.z) | ((u32)f2bf(a.w) << 16);
    o.z = (u32)f2bf(b.x) | ((u32)f2bf(b.y) << 16);
    o.w = (u32)f2bf(b.z) | ((u32)f2bf(b.w) << 16);
    ((uint4*)dst)[idx] = o;
}

// ---------------------------------------------------------------------------
// kNN: one block (256 thr = 4 waves) per FOUR queries (round-10 structure,
// HW-validated). Stable-argsort-exact semantics, self at rank 0 dropped.
// ---------------------------------------------------------------------------
__global__ __launch_bounds__(256) void knn_kernel(const float* __restrict__ coords,
                                                  u16* __restrict__ nn_out) {
    __shared__ u32 distd[4][2048];        // 32 KB  [query][pos*256+thread]
    __shared__ u16 idxs [4][2048];        // 16 KB
    const int blk = blockIdx.x;           // b*512 + qg
    const int b   = blk >> 9;
    const int q0  = (blk & 511) * 4;
    const int t   = threadIdx.x;
    const int wid = t >> 6, lane = t & 63;

    const float* cb = coords + (size_t)b * SEQ * 3;

    float qx[4], qy[4], qz[4];
#pragma unroll
    for (int qq = 0; qq < 4; ++qq) {
        qx[qq] = cb[(q0 + qq) * 3 + 0];
        qy[qq] = cb[(q0 + qq) * 3 + 1];
        qz[qq] = cb[(q0 + qq) * 3 + 2];
    }
    float cx[8], cy[8], cz[8];
#pragma unroll
    for (int i = 0; i < 8; ++i) {
        int c = i * 256 + t;
        cx[i] = cb[c * 3 + 0];
        cy[i] = cb[c * 3 + 1];
        cz[i] = cb[c * 3 + 2];
    }

#pragma unroll
    for (int qq = 0; qq < 4; ++qq) {
        u64 key[8];
#pragma unroll
        for (int i = 0; i < 8; ++i) {
            int c = i * 256 + t;
            float dx = __fsub_rn(cx[i], qx[qq]);
            float dy = __fsub_rn(cy[i], qy[qq]);
            float dz = __fsub_rn(cz[i], qz[qq]);
            // numpy order: (dx*dx + dy*dy) + dz*dz, no FMA, IEEE sqrt
            float d2 = __fadd_rn(__fadd_rn(__fmul_rn(dx, dx), __fmul_rn(dy, dy)),
                                 __fmul_rn(dz, dz));
            float dist = __fsqrt_rn(d2);
            key[i] = (((u64)__float_as_uint(dist)) << 32) | (u32)c;   // self included
        }
#pragma unroll
        for (int k = 2; k <= 8; k <<= 1) {
#pragma unroll
            for (int j = k >> 1; j > 0; j >>= 1) {
#pragma unroll
                for (int i = 0; i < 8; ++i) {
                    int ixj = i ^ j;
                    if (ixj > i) {
                        bool up = (i & k) == 0;
                        u64 a = key[i], c2 = key[ixj];
                        bool sw = up ? (a > c2) : (a < c2);
                        u64 lo = sw ? c2 : a;
                        u64 hi = sw ? a : c2;
                        key[i] = lo;
                        key[ixj] = hi;
                    }
                }
            }
        }
#pragma unroll
        for (int i = 0; i < 8; ++i) {
            distd[qq][i * 256 + t] = (u32)(key[i] >> 32);
            idxs [qq][i * 256 + t] = (u16)key[i];
        }
    }
    __syncthreads();

    u64 h[4]; int p[4];
#pragma unroll
    for (int w = 0; w < 4; ++w) {
        int s = lane + 64 * w;
        h[w] = (((u64)distd[wid][s]) << 32) | idxs[wid][s];
        p[w] = 1;
    }

    u32 my = 0;
#pragma unroll 1
    for (int r = 0; r < KNN + 1; ++r) {          // rank 0 = self slot, dropped
        u64 lm = min_u64(min_u64(h[0], h[1]), min_u64(h[2], h[3]));
        u32 d = (u32)(lm >> 32);
        u32 m = d;
        m = min(m, (u32)__shfl_xor((int)m, 1, 64));
        m = min(m, (u32)__shfl_xor((int)m, 2, 64));
        m = min(m, (u32)__shfl_xor((int)m, 4, 64));
        m = min(m, (u32)__shfl_xor((int)m, 8, 64));
        m = min(m, (u32)__shfl_xor((int)m, 16, 64));
        m = min(m, (u32)__shfl_xor((int)m, 32, 64));
        u64 mask = __ballot(d == m);
        u32 win_idx;
        if (__popcll(mask) == 1) {               // common case: unique dist
            int winner = __ffsll((long long)mask) - 1;
            win_idx = (u32)__shfl((int)(u32)lm, winner, 64);
        } else {                                 // rare: dist tie -> min idx
            u32 ti = (d == m) ? (u32)lm : 0xFFFFFFFFu;
            ti = min(ti, (u32)__shfl_xor((int)ti, 1, 64));
            ti = min(ti, (u32)__shfl_xor((int)ti, 2, 64));
            ti = min(ti, (u32)__shfl_xor((int)ti, 4, 64));
            ti = min(ti, (u32)__shfl_xor((int)ti, 8, 64));
            ti = min(ti, (u32)__shfl_xor((int)ti, 16, 64));
            ti = min(ti, (u32)__shfl_xor((int)ti, 32, 64));
            win_idx = ti;
        }
        if (r == lane + 1) my = win_idx;
        u64 mfull = (((u64)m) << 32) | win_idx;
#pragma unroll
        for (int w = 0; w < 4; ++w) {
            if (h[w] == mfull) {
                int s = lane + 64 * w;
                h[w] = (p[w] < 8) ? ((((u64)distd[wid][p[w] * 256 + s]) << 32)
                                     | idxs[wid][p[w] * 256 + s])
                                  : ~0ull;
                ++p[w];
            }
        }
    }
    if (lane < KNN)
        nn_out[((size_t)(b << 11) + q0 + wid) * KNN + lane] = (u16)(my & 0x7FF);
}

// ---------------------------------------------------------------------------
// LDS-tiled MFMA GEMM (m93 structure): out[m,n] = sum_k A[m,k]*W[n,k].
// 128x128 block tile, BK=32, 256 thr = 4 waves (2x2), 64x64 wave tile.
// z=0 -> q (fp32 to d_out); z=1,2 -> k,v (bf16 to ws).
// ---------------------------------------------------------------------------
__global__ __launch_bounds__(256) void gemm_mfma(const bf16_t* __restrict__ xb,
                                                 const bf16_t* __restrict__ wqb,
                                                 const bf16_t* __restrict__ wkb,
                                                 const bf16_t* __restrict__ wvb,
                                                 float* __restrict__ qout,
                                                 bf16_t* __restrict__ kvout) {
    __shared__ __align__(16) bf16_t As[128 * 32];
    __shared__ __align__(16) bf16_t Bs[128 * 32];
    const int z = blockIdx.z;
    const bf16_t* W = (z == 0) ? wqb : (z == 1) ? wkb : wvb;
    const int tid  = threadIdx.x;
    const int wid  = tid >> 6, lane = tid & 63;
    const int m16  = lane & 15, quad = lane >> 4;
    const int wm   = (wid & 1) * 64;
    const int wn   = (wid >> 1) * 64;
    const int m0   = blockIdx.y * 128;
    const int n0   = blockIdx.x * 128;

    const int sr = tid >> 2, sc = (tid & 3) * 8;
    const bf16_t* agp = xb + (size_t)(m0 + sr) * FDIM + sc;
    const bf16_t* bgp = W  + (size_t)(n0 + sr) * FDIM + sc;

    f32x4 acc[4][4];
#pragma unroll
    for (int i = 0; i < 4; ++i)
#pragma unroll
        for (int j = 0; j < 4; ++j) acc[i][j] = (f32x4){0.f, 0.f, 0.f, 0.f};

#pragma unroll 1
    for (int k0 = 0; k0 < FDIM; k0 += 32) {
        uint4 a0 = *(const uint4*)(agp + k0);
        uint4 a1 = *(const uint4*)(agp + (size_t)64 * FDIM + k0);
        uint4 b0 = *(const uint4*)(bgp + k0);
        uint4 b1 = *(const uint4*)(bgp + (size_t)64 * FDIM + k0);
        __syncthreads();
        *(uint4*)(As + sr * 32 + sc)        = a0;
        *(uint4*)(As + (sr + 64) * 32 + sc) = a1;
        *(uint4*)(Bs + sr * 32 + sc)        = b0;
        *(uint4*)(Bs + (sr + 64) * 32 + sc) = b1;
        __syncthreads();

        short8 af[4], bfr[4];
#pragma unroll
        for (int i = 0; i < 4; ++i)
            af[i] = *(const short8*)(As + (wm + i * 16 + m16) * 32 + quad * 8);
#pragma unroll
        for (int j = 0; j < 4; ++j)
            bfr[j] = *(const short8*)(Bs + (wn + j * 16 + m16) * 32 + quad * 8);
#pragma unroll
        for (int i = 0; i < 4; ++i)
#pragma unroll
            for (int j = 0; j < 4; ++j)
                acc[i][j] = __builtin_amdgcn_mfma_f32_16x16x32_bf16(af[i], bfr[j],
                                                                    acc[i][j], 0, 0, 0);
    }

    if (z == 0) {
#pragma unroll
        for (int i = 0; i < 4; ++i) {
            const int rowb = m0 + wm + i * 16 + quad * 4;
#pragma unroll
            for (int r = 0; r < 4; ++r) {
                float* orow = qout + (size_t)(rowb + r) * FDIM + n0 + wn + m16;
                orow[ 0] = acc[i][0][r]; orow[16] = acc[i][1][r];
                orow[32] = acc[i][2][r]; orow[48] = acc[i][3][r];
            }
        }
    } else {
        bf16_t* base = kvout + (size_t)(z - 1) * BSF;
#pragma unroll
        for (int i = 0; i < 4; ++i) {
            const int rowb = m0 + wm + i * 16 + quad * 4;
#pragma unroll
            for (int r = 0; r < 4; ++r) {
                bf16_t* orow = base + (size_t)(rowb + r) * FDIM + n0 + wn + m16;
                orow[ 0] = f2bf(acc[i][0][r]); orow[16] = f2bf(acc[i][1][r]);
                orow[32] = f2bf(acc[i][2][r]); orow[48] = f2bf(acc[i][3][r]);
            }
        }
    }
}

// ---------------------------------------------------------------------------
// Attention, ALL batches: block per (b,q), 512 thr = 8 waves, wave per head.
// XCD swizzle (r11: halved FETCH) kept. PV restructured (r12): wave split as
// g=lane>>4 (4 neighbor-groups of 8) x l=lane&15 (4 dims/lane via uint2
// loads); 8 iterations instead of 32, 8B loads instead of 2B, then 8-shuffle
// cross-group reduce + float4 store. fp32 reassociation only.
// ---------------------------------------------------------------------------
__global__ __launch_bounds__(512) void attn_kernel(const bf16_t* __restrict__ kv,
                                                   const u16* __restrict__ nn,
                                                   float* __restrict__ out) {
    __shared__ float qs[FDIM];
    __shared__ int   sidx[KNN];
    __shared__ float wls[NHEAD][KNN];
    const int i   = blockIdx.x;
    const int b   = (i & 7) >> 1;                         // XCD pair -> batch
    const int qi  = ((i >> 3) << 1) | (i & 1);            // 0..2047, bijective
    const int blk = (b << 11) | qi;
    const int tid = threadIdx.x;
    const int h = tid >> 6, lane = tid & 63;

    qs[tid] = out[(size_t)blk * FDIM + tid];                  // own q row
    if (tid < KNN) sidx[tid] = (int)nn[(size_t)blk * KNN + tid] & (SEQ - 1);
    __syncthreads();

    // ---- QK + softmax (unchanged, HW-validated) ----
    const int j = lane & 31, half = lane >> 5;
    const bf16_t* kreg = kv + ((size_t)((b << 11) + sidx[j])) * FDIM + h * HDIM + half * 32;
    const float* qp = &qs[h * HDIM + half * 32];
    float acc = 0.f;
#pragma unroll
    for (int d = 0; d < 32; d += 8) {
        uint4 kvv = *(const uint4*)(kreg + d);   // 8 bf16
        float f0, f1, f2, f3, f4, f5, f6, f7;
        bf2x2(kvv.x, f0, f1); bf2x2(kvv.y, f2, f3);
        bf2x2(kvv.z, f4, f5); bf2x2(kvv.w, f6, f7);
        acc += qp[d + 0] * f0 + qp[d + 1] * f1 + qp[d + 2] * f2 + qp[d + 3] * f3
             + qp[d + 4] * f4 + qp[d + 5] * f5 + qp[d + 6] * f6 + qp[d + 7] * f7;
    }
    acc += __shfl_xor(acc, 32, 64);
    float s = acc * 0.125f;                 // 1/sqrt(64)
    float m = s;
    m = fmaxf(m, __shfl_xor(m, 1, 64));
    m = fmaxf(m, __shfl_xor(m, 2, 64));
    m = fmaxf(m, __shfl_xor(m, 4, 64));
    m = fmaxf(m, __shfl_xor(m, 8, 64));
    m = fmaxf(m, __shfl_xor(m, 16, 64));
    float e = __expf(s - m);
    float sum = e;
    sum += __shfl_xor(sum, 1, 64);
    sum += __shfl_xor(sum, 2, 64);
    sum += __shfl_xor(sum, 4, 64);
    sum += __shfl_xor(sum, 8, 64);
    sum += __shfl_xor(sum, 16, 64);
    float w = e / sum;
    if (half == 0) wls[h][j] = w;
    __syncthreads();

    // ---- PV: g = neighbor-group (8 j's), l = dim-quad (4 dims via uint2) ----
    const int g = lane >> 4, l = lane & 15;
    const bf16_t* vbase = kv + BSF + ((size_t)(b << 11)) * FDIM + h * HDIM + l * 4;
    float o0 = 0.f, o1 = 0.f, o2 = 0.f, o3 = 0.f;
#pragma unroll
    for (int t2 = 0; t2 < 8; ++t2) {
        const int j2 = g * 8 + t2;
        const float wj = wls[h][j2];
        const int row = sidx[j2];
        uint2 vv = *(const uint2*)(vbase + (size_t)row * FDIM);   // 4 bf16
        float f0, f1, f2, f3;
        bf2x2(vv.x, f0, f1); bf2x2(vv.y, f2, f3);
        o0 += wj * f0; o1 += wj * f1; o2 += wj * f2; o3 += wj * f3;
    }
    o0 += __shfl_xor(o0, 16, 64); o0 += __shfl_xor(o0, 32, 64);
    o1 += __shfl_xor(o1, 16, 64); o1 += __shfl_xor(o1, 32, 64);
    o2 += __shfl_xor(o2, 16, 64); o2 += __shfl_xor(o2, 32, 64);
    o3 += __shfl_xor(o3, 16, 64); o3 += __shfl_xor(o3, 32, 64);
    if (g == 0) {
        float4 ov = make_float4(o0, o1, o2, o3);
        *(float4*)(out + (size_t)blk * FDIM + h * HDIM + l * 4) = ov;
    }
}

// ---------------------------------------------------------------------------
// metric = mean_s(k) = (mean_s x) @ Wk^T  (linearity), fp32 from raw inputs
// ---------------------------------------------------------------------------
__global__ __launch_bounds__(256) void xbar_kernel(const float* __restrict__ x,
                                                   float* __restrict__ xbar) {
    const int b = blockIdx.x, chunk = blockIdx.y;   // 32 chunks of 64 rows
    const int tid = threadIdx.x;
    const float* xp = x + (size_t)b * SF + (size_t)chunk * 64 * FDIM;
    float s0 = 0.f, s1 = 0.f;
    for (int r = 0; r < 64; ++r) {
        s0 += xp[(size_t)r * FDIM + tid];
        s1 += xp[(size_t)r * FDIM + tid + 256];
    }
    atomicAdd(&xbar[b * FDIM + tid],       s0 * (1.f / 2048.f));
    atomicAdd(&xbar[b * FDIM + tid + 256], s1 * (1.f / 2048.f));
}

__global__ __launch_bounds__(256) void metric_kernel(const float* __restrict__ xbar,
                                                     const float* __restrict__ Wk,
                                                     float* __restrict__ metric) {
    const int o = blockIdx.x * 256 + threadIdx.x;   // 2048 outputs
    const int b = o >> 9, f = o & 511;
    const float* xb = xbar + b * FDIM;
    const float* wr = Wk + (size_t)f * FDIM;
    float acc = 0.f;
#pragma unroll 4
    for (int kk = 0; kk < FDIM; kk += 4) {
        float4 wv = *(const float4*)(wr + kk);
        acc += xb[kk + 0] * wv.x + xb[kk + 1] * wv.y
             + xb[kk + 2] * wv.z + xb[kk + 3] * wv.w;
    }
    metric[o] = acc;
}

// ---------------------------------------------------------------------------
extern "C" void kernel_launch(void* const* d_in, const int* in_sizes, int n_in,
                              void* d_out, int out_size, void* d_ws, size_t ws_size,
                              hipStream_t stream) {
    const float* x      = (const float*)d_in[0];
    const float* coords = (const float*)d_in[1];
    const float* Wq     = (const float*)d_in[2];
    const float* Wk     = (const float*)d_in[3];
    const float* Wv     = (const float*)d_in[4];
    float* out    = (float*)d_out;
    float* metric = out + BSF;

    // ws layout (26.0 MiB):
    //   xb bf16 BSF (8 MiB) | wqb/wkb/wvb bf16 (1.5 MiB) | kv bf16 2*BSF (16 MiB)
    //   | nn u16 (0.5 MiB) | xbar f32 (8 KiB)
    char* p = (char*)d_ws;
    bf16_t* xb   = (bf16_t*)p;                       p += BSF * sizeof(bf16_t);
    bf16_t* wqb  = (bf16_t*)p;                       p += (size_t)FDIM * FDIM * sizeof(bf16_t);
    bf16_t* wkb  = (bf16_t*)p;                       p += (size_t)FDIM * FDIM * sizeof(bf16_t);
    bf16_t* wvb  = (bf16_t*)p;                       p += (size_t)FDIM * FDIM * sizeof(bf16_t);
    bf16_t* kv   = (bf16_t*)p;                       p += 2 * BSF * sizeof(bf16_t);
    u16*    nn   = (u16*)p;                          p += (size_t)BATCH * SEQ * KNN * sizeof(u16);
    float*  xbar = (float*)p;

    cast_kernel<<<dim3(BSF / 8 / 256, 1, 4), 256, 0, stream>>>(x, Wq, Wk, Wv,
                                                               xb, wqb, wkb, wvb);
    knn_kernel<<<(BATCH * SEQ) / 4, 256, 0, stream>>>(coords, nn);

    // q -> d_out (fp32), k/v -> ws (bf16); one dispatch, 128x128 tiles
    gemm_mfma<<<dim3(FDIM / 128, (BATCH * SEQ) / 128, 3), 256, 0, stream>>>(
        xb, wqb, wkb, wvb, out, kv);

    hipMemsetAsync(xbar, 0, BATCH * FDIM * sizeof(float), stream);
    xbar_kernel<<<dim3(BATCH, 32), 256, 0, stream>>>(x, xbar);
    metric_kernel<<<(BATCH * NHEAD * HDIM) / 256, 256, 0, stream>>>(xbar, Wk, metric);

    attn_kernel<<<BATCH * SEQ, 512, 0, stream>>>(kv, nn, out);
}

// Round 13
// 235.380 us; speedup vs baseline: 1.1339x; 1.0326x over previous
//
#include <hip/hip_runtime.h>
#include <stdint.h>

#define BATCH 4
#define SEQ   2048
#define FDIM  512
#define NHEAD 8
#define HDIM  64
#define KNN   32

typedef unsigned int u32;
typedef unsigned long long u64;
typedef unsigned short u16;
typedef unsigned short bf16_t;

typedef __attribute__((ext_vector_type(8))) short short8;   // 8 bf16 = 4 VGPRs
typedef __attribute__((ext_vector_type(4))) float f32x4;

#define SF  ((size_t)SEQ * FDIM)            // 1,048,576 per-batch elements
#define BSF ((size_t)BATCH * SF)            // 4,194,304

__device__ __forceinline__ bf16_t f2bf(float f) {
    u32 x = __float_as_uint(f);
    return (bf16_t)((x + 0x7FFFu + ((x >> 16) & 1u)) >> 16);   // RNE
}
__device__ __forceinline__ float bf2f(bf16_t u) { return __uint_as_float(((u32)u) << 16); }
__device__ __forceinline__ void bf2x2(u32 p, float& a, float& b) {
    a = __uint_as_float(p << 16);          // element 2i (low u16)
    b = __uint_as_float(p & 0xFFFF0000u);  // element 2i+1 (high u16)
}
__device__ __forceinline__ u64 min_u64(u64 a, u64 b) { return a < b ? a : b; }

// ---------------------------------------------------------------------------
// Cast x / Wq / Wk / Wv (fp32) -> bf16, 8 elements/thread. grid.z selects.
// ---------------------------------------------------------------------------
__global__ __launch_bounds__(256) void cast_kernel(const float* __restrict__ x,
                                                   const float* __restrict__ wq,
                                                   const float* __restrict__ wk,
                                                   const float* __restrict__ wv,
                                                   bf16_t* __restrict__ xb,
                                                   bf16_t* __restrict__ wqb,
                                                   bf16_t* __restrict__ wkb,
                                                   bf16_t* __restrict__ wvb) {
    const int z = blockIdx.z;
    const float* src = (z == 0) ? x : (z == 1) ? wq : (z == 2) ? wk : wv;
    bf16_t* dst      = (z == 0) ? xb : (z == 1) ? wqb : (z == 2) ? wkb : wvb;
    const size_t cnt8 = (z == 0) ? (BSF / 8) : ((size_t)FDIM * FDIM / 8);
    size_t idx = (size_t)blockIdx.x * 256 + threadIdx.x;
    if (idx >= cnt8) return;
    const float4 a = ((const float4*)src)[idx * 2 + 0];
    const float4 b = ((const float4*)src)[idx * 2 + 1];
    uint4 o;
    o.x = (u32)f2bf(a.x) | ((u32)f2bf(a.y) << 16);
    o.y = (u32)f2bf(a.z) | ((u32)f2bf(a.w) << 16);
    o.z = (u32)f2bf(b.x) | ((u32)f2bf(b.y) << 16);
    o.w = (u32)f2bf(b.z) | ((u32)f2bf(b.w) << 16);
    ((uint4*)dst)[idx] = o;
}

// ---------------------------------------------------------------------------
// kNN: one block (256 thr = 4 waves) per FOUR queries (round-10 structure,
// HW-validated). Stable-argsort-exact semantics, self at rank 0 dropped.
// ---------------------------------------------------------------------------
__global__ __launch_bounds__(256) void knn_kernel(const float* __restrict__ coords,
                                                  u16* __restrict__ nn_out) {
    __shared__ u32 distd[4][2048];        // 32 KB  [query][pos*256+thread]
    __shared__ u16 idxs [4][2048];        // 16 KB
    const int blk = blockIdx.x;           // b*512 + qg
    const int b   = blk >> 9;
    const int q0  = (blk & 511) * 4;
    const int t   = threadIdx.x;
    const int wid = t >> 6, lane = t & 63;

    const float* cb = coords + (size_t)b * SEQ * 3;

    float qx[4], qy[4], qz[4];
#pragma unroll
    for (int qq = 0; qq < 4; ++qq) {
        qx[qq] = cb[(q0 + qq) * 3 + 0];
        qy[qq] = cb[(q0 + qq) * 3 + 1];
        qz[qq] = cb[(q0 + qq) * 3 + 2];
    }
    float cx[8], cy[8], cz[8];
#pragma unroll
    for (int i = 0; i < 8; ++i) {
        int c = i * 256 + t;
        cx[i] = cb[c * 3 + 0];
        cy[i] = cb[c * 3 + 1];
        cz[i] = cb[c * 3 + 2];
    }

#pragma unroll
    for (int qq = 0; qq < 4; ++qq) {
        u64 key[8];
#pragma unroll
        for (int i = 0; i < 8; ++i) {
            int c = i * 256 + t;
            float dx = __fsub_rn(cx[i], qx[qq]);
            float dy = __fsub_rn(cy[i], qy[qq]);
            float dz = __fsub_rn(cz[i], qz[qq]);
            // numpy order: (dx*dx + dy*dy) + dz*dz, no FMA, IEEE sqrt
            float d2 = __fadd_rn(__fadd_rn(__fmul_rn(dx, dx), __fmul_rn(dy, dy)),
                                 __fmul_rn(dz, dz));
            float dist = __fsqrt_rn(d2);
            key[i] = (((u64)__float_as_uint(dist)) << 32) | (u32)c;   // self included
        }
#pragma unroll
        for (int k = 2; k <= 8; k <<= 1) {
#pragma unroll
            for (int j = k >> 1; j > 0; j >>= 1) {
#pragma unroll
                for (int i = 0; i < 8; ++i) {
                    int ixj = i ^ j;
                    if (ixj > i) {
                        bool up = (i & k) == 0;
                        u64 a = key[i], c2 = key[ixj];
                        bool sw = up ? (a > c2) : (a < c2);
                        u64 lo = sw ? c2 : a;
                        u64 hi = sw ? a : c2;
                        key[i] = lo;
                        key[ixj] = hi;
                    }
                }
            }
        }
#pragma unroll
        for (int i = 0; i < 8; ++i) {
            distd[qq][i * 256 + t] = (u32)(key[i] >> 32);
            idxs [qq][i * 256 + t] = (u16)key[i];
        }
    }
    __syncthreads();

    u64 h[4]; int p[4];
#pragma unroll
    for (int w = 0; w < 4; ++w) {
        int s = lane + 64 * w;
        h[w] = (((u64)distd[wid][s]) << 32) | idxs[wid][s];
        p[w] = 1;
    }

    u32 my = 0;
#pragma unroll 1
    for (int r = 0; r < KNN + 1; ++r) {          // rank 0 = self slot, dropped
        u64 lm = min_u64(min_u64(h[0], h[1]), min_u64(h[2], h[3]));
        u32 d = (u32)(lm >> 32);
        u32 m = d;
        m = min(m, (u32)__shfl_xor((int)m, 1, 64));
        m = min(m, (u32)__shfl_xor((int)m, 2, 64));
        m = min(m, (u32)__shfl_xor((int)m, 4, 64));
        m = min(m, (u32)__shfl_xor((int)m, 8, 64));
        m = min(m, (u32)__shfl_xor((int)m, 16, 64));
        m = min(m, (u32)__shfl_xor((int)m, 32, 64));
        u64 mask = __ballot(d == m);
        u32 win_idx;
        if (__popcll(mask) == 1) {               // common case: unique dist
            int winner = __ffsll((long long)mask) - 1;
            win_idx = (u32)__shfl((int)(u32)lm, winner, 64);
        } else {                                 // rare: dist tie -> min idx
            u32 ti = (d == m) ? (u32)lm : 0xFFFFFFFFu;
            ti = min(ti, (u32)__shfl_xor((int)ti, 1, 64));
            ti = min(ti, (u32)__shfl_xor((int)ti, 2, 64));
            ti = min(ti, (u32)__shfl_xor((int)ti, 4, 64));
            ti = min(ti, (u32)__shfl_xor((int)ti, 8, 64));
            ti = min(ti, (u32)__shfl_xor((int)ti, 16, 64));
            ti = min(ti, (u32)__shfl_xor((int)ti, 32, 64));
            win_idx = ti;
        }
        if (r == lane + 1) my = win_idx;
        u64 mfull = (((u64)m) << 32) | win_idx;
#pragma unroll
        for (int w = 0; w < 4; ++w) {
            if (h[w] == mfull) {
                int s = lane + 64 * w;
                h[w] = (p[w] < 8) ? ((((u64)distd[wid][p[w] * 256 + s]) << 32)
                                     | idxs[wid][p[w] * 256 + s])
                                  : ~0ull;
                ++p[w];
            }
        }
    }
    if (lane < KNN)
        nn_out[((size_t)(b << 11) + q0 + wid) * KNN + lane] = (u16)(my & 0x7FF);
}

// ---------------------------------------------------------------------------
// LDS-tiled MFMA GEMM (m93 structure): out[m,n] = sum_k A[m,k]*W[n,k].
// 128x128 block tile, BK=32, 256 thr = 4 waves (2x2), 64x64 wave tile.
// z=0 -> q (fp32 to d_out); z=1,2 -> k,v (bf16 to ws).
// ---------------------------------------------------------------------------
__global__ __launch_bounds__(256) void gemm_mfma(const bf16_t* __restrict__ xb,
                                                 const bf16_t* __restrict__ wqb,
                                                 const bf16_t* __restrict__ wkb,
                                                 const bf16_t* __restrict__ wvb,
                                                 float* __restrict__ qout,
                                                 bf16_t* __restrict__ kvout) {
    __shared__ __align__(16) bf16_t As[128 * 32];
    __shared__ __align__(16) bf16_t Bs[128 * 32];
    const int z = blockIdx.z;
    const bf16_t* W = (z == 0) ? wqb : (z == 1) ? wkb : wvb;
    const int tid  = threadIdx.x;
    const int wid  = tid >> 6, lane = tid & 63;
    const int m16  = lane & 15, quad = lane >> 4;
    const int wm   = (wid & 1) * 64;
    const int wn   = (wid >> 1) * 64;
    const int m0   = blockIdx.y * 128;
    const int n0   = blockIdx.x * 128;

    const int sr = tid >> 2, sc = (tid & 3) * 8;
    const bf16_t* agp = xb + (size_t)(m0 + sr) * FDIM + sc;
    const bf16_t* bgp = W  + (size_t)(n0 + sr) * FDIM + sc;

    f32x4 acc[4][4];
#pragma unroll
    for (int i = 0; i < 4; ++i)
#pragma unroll
        for (int j = 0; j < 4; ++j) acc[i][j] = (f32x4){0.f, 0.f, 0.f, 0.f};

#pragma unroll 1
    for (int k0 = 0; k0 < FDIM; k0 += 32) {
        uint4 a0 = *(const uint4*)(agp + k0);
        uint4 a1 = *(const uint4*)(agp + (size_t)64 * FDIM + k0);
        uint4 b0 = *(const uint4*)(bgp + k0);
        uint4 b1 = *(const uint4*)(bgp + (size_t)64 * FDIM + k0);
        __syncthreads();
        *(uint4*)(As + sr * 32 + sc)        = a0;
        *(uint4*)(As + (sr + 64) * 32 + sc) = a1;
        *(uint4*)(Bs + sr * 32 + sc)        = b0;
        *(uint4*)(Bs + (sr + 64) * 32 + sc) = b1;
        __syncthreads();

        short8 af[4], bfr[4];
#pragma unroll
        for (int i = 0; i < 4; ++i)
            af[i] = *(const short8*)(As + (wm + i * 16 + m16) * 32 + quad * 8);
#pragma unroll
        for (int j = 0; j < 4; ++j)
            bfr[j] = *(const short8*)(Bs + (wn + j * 16 + m16) * 32 + quad * 8);
#pragma unroll
        for (int i = 0; i < 4; ++i)
#pragma unroll
            for (int j = 0; j < 4; ++j)
                acc[i][j] = __builtin_amdgcn_mfma_f32_16x16x32_bf16(af[i], bfr[j],
                                                                    acc[i][j], 0, 0, 0);
    }

    if (z == 0) {
#pragma unroll
        for (int i = 0; i < 4; ++i) {
            const int rowb = m0 + wm + i * 16 + quad * 4;
#pragma unroll
            for (int r = 0; r < 4; ++r) {
                float* orow = qout + (size_t)(rowb + r) * FDIM + n0 + wn + m16;
                orow[ 0] = acc[i][0][r]; orow[16] = acc[i][1][r];
                orow[32] = acc[i][2][r]; orow[48] = acc[i][3][r];
            }
        }
    } else {
        bf16_t* base = kvout + (size_t)(z - 1) * BSF;
#pragma unroll
        for (int i = 0; i < 4; ++i) {
            const int rowb = m0 + wm + i * 16 + quad * 4;
#pragma unroll
            for (int r = 0; r < 4; ++r) {
                bf16_t* orow = base + (size_t)(rowb + r) * FDIM + n0 + wn + m16;
                orow[ 0] = f2bf(acc[i][0][r]); orow[16] = f2bf(acc[i][1][r]);
                orow[32] = f2bf(acc[i][2][r]); orow[48] = f2bf(acc[i][3][r]);
            }
        }
    }
}

// ---------------------------------------------------------------------------
// Attention v3: BARRIER-FREE. One wave per (query, head); 256-thr blocks =
// 4 independent waves; no __syncthreads. nn indices + softmax weights live
// in registers and move via shuffles; q slice in a private per-wave LDS slot
// (DS ops are in-order within a wave; explicit lgkmcnt(0) + wave_barrier).
// Each wave reads exactly the out-slice it later writes (no cross-wave
// hazard). XCD swizzle kept (bijective). Math identical to r12 (HW-valid).
// ---------------------------------------------------------------------------
__global__ __launch_bounds__(256) void attn_kernel(const bf16_t* __restrict__ kv,
                                                   const u16* __restrict__ nn,
                                                   float* __restrict__ out) {
    __shared__ float qsl[4][64];                          // 1 KB, per-wave slot
    const int i   = blockIdx.x;                           // 0..16383
    const int b   = (i & 7) >> 1;                         // XCD pair -> batch
    const int jb  = ((i >> 3) << 1) | (i & 1);            // 0..4095, bijective
    const int tid = threadIdx.x;
    const int wid = tid >> 6, lane = tid & 63;
    const int gid = (jb << 2) | wid;                      // 0..16383 per batch
    const int qi  = gid >> 3, h = gid & 7;
    const int blk = (b << 11) | qi;

    int sreg = 0;
    if (lane < KNN) sreg = (int)nn[(size_t)blk * KNN + lane] & (SEQ - 1);
    qsl[wid][lane] = out[(size_t)blk * FDIM + h * HDIM + lane];   // own q slice
    __asm__ volatile("s_waitcnt lgkmcnt(0)" ::: "memory");
    __builtin_amdgcn_wave_barrier();

    // ---- QK: 2 lanes per neighbor (j, half), 32 dims each ----
    const int j = lane & 31, half = lane >> 5;
    const int rowj = __shfl(sreg, j, 64);
    const bf16_t* kreg = kv + ((size_t)((b << 11) + rowj)) * FDIM + h * HDIM + half * 32;
    const float* qp = &qsl[wid][half * 32];
    float acc = 0.f;
#pragma unroll
    for (int d = 0; d < 32; d += 8) {
        uint4 kvv = *(const uint4*)(kreg + d);   // 8 bf16
        float f0, f1, f2, f3, f4, f5, f6, f7;
        bf2x2(kvv.x, f0, f1); bf2x2(kvv.y, f2, f3);
        bf2x2(kvv.z, f4, f5); bf2x2(kvv.w, f6, f7);
        acc += qp[d + 0] * f0 + qp[d + 1] * f1 + qp[d + 2] * f2 + qp[d + 3] * f3
             + qp[d + 4] * f4 + qp[d + 5] * f5 + qp[d + 6] * f6 + qp[d + 7] * f7;
    }
    acc += __shfl_xor(acc, 32, 64);
    float s = acc * 0.125f;                 // 1/sqrt(64)
    float m = s;
    m = fmaxf(m, __shfl_xor(m, 1, 64));
    m = fmaxf(m, __shfl_xor(m, 2, 64));
    m = fmaxf(m, __shfl_xor(m, 4, 64));
    m = fmaxf(m, __shfl_xor(m, 8, 64));
    m = fmaxf(m, __shfl_xor(m, 16, 64));
    float e = __expf(s - m);
    float sum = e;
    sum += __shfl_xor(sum, 1, 64);
    sum += __shfl_xor(sum, 2, 64);
    sum += __shfl_xor(sum, 4, 64);
    sum += __shfl_xor(sum, 8, 64);
    sum += __shfl_xor(sum, 16, 64);
    float w = e / sum;                      // valid per j on lanes j and j+32

    // ---- PV: g = neighbor-group of 8, l = dim-quad (4 dims via uint2) ----
    const int g = lane >> 4, l = lane & 15;
    const bf16_t* vbase = kv + BSF + ((size_t)(b << 11)) * FDIM + h * HDIM + l * 4;
    float o0 = 0.f, o1 = 0.f, o2 = 0.f, o3 = 0.f;
#pragma unroll
    for (int t2 = 0; t2 < 8; ++t2) {
        const int j2 = (g << 3) | t2;
        const float wj = __shfl(w, j2, 64);
        const int row = __shfl(sreg, j2, 64);
        uint2 vv = *(const uint2*)(vbase + (size_t)row * FDIM);   // 4 bf16
        float f0, f1, f2, f3;
        bf2x2(vv.x, f0, f1); bf2x2(vv.y, f2, f3);
        o0 += wj * f0; o1 += wj * f1; o2 += wj * f2; o3 += wj * f3;
    }
    o0 += __shfl_xor(o0, 16, 64); o0 += __shfl_xor(o0, 32, 64);
    o1 += __shfl_xor(o1, 16, 64); o1 += __shfl_xor(o1, 32, 64);
    o2 += __shfl_xor(o2, 16, 64); o2 += __shfl_xor(o2, 32, 64);
    o3 += __shfl_xor(o3, 16, 64); o3 += __shfl_xor(o3, 32, 64);
    if (g == 0) {
        float4 ov = make_float4(o0, o1, o2, o3);
        *(float4*)(out + (size_t)blk * FDIM + h * HDIM + l * 4) = ov;
    }
}

// ---------------------------------------------------------------------------
// metric = mean_s(k) = (mean_s x) @ Wk^T  (linearity), fp32 from raw inputs
// ---------------------------------------------------------------------------
__global__ __launch_bounds__(256) void xbar_kernel(const float* __restrict__ x,
                                                   float* __restrict__ xbar) {
    const int b = blockIdx.x, chunk = blockIdx.y;   // 32 chunks of 64 rows
    const int tid = threadIdx.x;
    const float* xp = x + (size_t)b * SF + (size_t)chunk * 64 * FDIM;
    float s0 = 0.f, s1 = 0.f;
    for (int r = 0; r < 64; ++r) {
        s0 += xp[(size_t)r * FDIM + tid];
        s1 += xp[(size_t)r * FDIM + tid + 256];
    }
    atomicAdd(&xbar[b * FDIM + tid],       s0 * (1.f / 2048.f));
    atomicAdd(&xbar[b * FDIM + tid + 256], s1 * (1.f / 2048.f));
}

__global__ __launch_bounds__(256) void metric_kernel(const float* __restrict__ xbar,
                                                     const float* __restrict__ Wk,
                                                     float* __restrict__ metric) {
    const int o = blockIdx.x * 256 + threadIdx.x;   // 2048 outputs
    const int b = o >> 9, f = o & 511;
    const float* xb = xbar + b * FDIM;
    const float* wr = Wk + (size_t)f * FDIM;
    float acc = 0.f;
#pragma unroll 4
    for (int kk = 0; kk < FDIM; kk += 4) {
        float4 wv = *(const float4*)(wr + kk);
        acc += xb[kk + 0] * wv.x + xb[kk + 1] * wv.y
             + xb[kk + 2] * wv.z + xb[kk + 3] * wv.w;
    }
    metric[o] = acc;
}

// ---------------------------------------------------------------------------
extern "C" void kernel_launch(void* const* d_in, const int* in_sizes, int n_in,
                              void* d_out, int out_size, void* d_ws, size_t ws_size,
                              hipStream_t stream) {
    const float* x      = (const float*)d_in[0];
    const float* coords = (const float*)d_in[1];
    const float* Wq     = (const float*)d_in[2];
    const float* Wk     = (const float*)d_in[3];
    const float* Wv     = (const float*)d_in[4];
    float* out    = (float*)d_out;
    float* metric = out + BSF;

    // ws layout (26.0 MiB):
    //   xb bf16 BSF (8 MiB) | wqb/wkb/wvb bf16 (1.5 MiB) | kv bf16 2*BSF (16 MiB)
    //   | nn u16 (0.5 MiB) | xbar f32 (8 KiB)
    char* p = (char*)d_ws;
    bf16_t* xb   = (bf16_t*)p;                       p += BSF * sizeof(bf16_t);
    bf16_t* wqb  = (bf16_t*)p;                       p += (size_t)FDIM * FDIM * sizeof(bf16_t);
    bf16_t* wkb  = (bf16_t*)p;                       p += (size_t)FDIM * FDIM * sizeof(bf16_t);
    bf16_t* wvb  = (bf16_t*)p;                       p += (size_t)FDIM * FDIM * sizeof(bf16_t);
    bf16_t* kv   = (bf16_t*)p;                       p += 2 * BSF * sizeof(bf16_t);
    u16*    nn   = (u16*)p;                          p += (size_t)BATCH * SEQ * KNN * sizeof(u16);
    float*  xbar = (float*)p;

    cast_kernel<<<dim3(BSF / 8 / 256, 1, 4), 256, 0, stream>>>(x, Wq, Wk, Wv,
                                                               xb, wqb, wkb, wvb);
    knn_kernel<<<(BATCH * SEQ) / 4, 256, 0, stream>>>(coords, nn);

    // q -> d_out (fp32), k/v -> ws (bf16); one dispatch, 128x128 tiles
    gemm_mfma<<<dim3(FDIM / 128, (BATCH * SEQ) / 128, 3), 256, 0, stream>>>(
        xb, wqb, wkb, wvb, out, kv);

    hipMemsetAsync(xbar, 0, BATCH * FDIM * sizeof(float), stream);
    xbar_kernel<<<dim3(BATCH, 32), 256, 0, stream>>>(x, xbar);
    metric_kernel<<<(BATCH * NHEAD * HDIM) / 256, 256, 0, stream>>>(xbar, Wk, metric);

    attn_kernel<<<(BATCH * SEQ * NHEAD) / 4, 256, 0, stream>>>(kv, nn, out);
}

// Round 14
// 199.939 us; speedup vs baseline: 1.3349x; 1.1773x over previous
//
#include <hip/hip_runtime.h>
#include <stdint.h>

#define BATCH 4
#define SEQ   2048
#define FDIM  512
#define NHEAD 8
#define HDIM  64
#define KNN   32

typedef unsigned int u32;
typedef unsigned long long u64;
typedef unsigned short u16;
typedef unsigned short bf16_t;

typedef __attribute__((ext_vector_type(8))) short short8;   // 8 bf16 = 4 VGPRs
typedef __attribute__((ext_vector_type(4))) float f32x4;

#define SF  ((size_t)SEQ * FDIM)            // 1,048,576 per-batch elements
#define BSF ((size_t)BATCH * SF)            // 4,194,304

__device__ __forceinline__ bf16_t f2bf(float f) {
    u32 x = __float_as_uint(f);
    return (bf16_t)((x + 0x7FFFu + ((x >> 16) & 1u)) >> 16);   // RNE
}
__device__ __forceinline__ float bf2f(bf16_t u) { return __uint_as_float(((u32)u) << 16); }
__device__ __forceinline__ void bf2x2(u32 p, float& a, float& b) {
    a = __uint_as_float(p << 16);          // element 2i (low u16)
    b = __uint_as_float(p & 0xFFFF0000u);  // element 2i+1 (high u16)
}
__device__ __forceinline__ u64 min_u64(u64 a, u64 b) { return a < b ? a : b; }
__device__ __forceinline__ u64 shfl_xor_u64(u64 v, int m) {
    int lo = __shfl_xor((int)(u32)v, m, 64);
    int hi = __shfl_xor((int)(u32)(v >> 32), m, 64);
    return (((u64)(u32)hi) << 32) | (u32)lo;
}

// ---------------------------------------------------------------------------
// Cast x / Wq / Wk / Wv (fp32) -> bf16, 8 elements/thread. grid.z selects.
// ---------------------------------------------------------------------------
__global__ __launch_bounds__(256) void cast_kernel(const float* __restrict__ x,
                                                   const float* __restrict__ wq,
                                                   const float* __restrict__ wk,
                                                   const float* __restrict__ wv,
                                                   bf16_t* __restrict__ xb,
                                                   bf16_t* __restrict__ wqb,
                                                   bf16_t* __restrict__ wkb,
                                                   bf16_t* __restrict__ wvb) {
    const int z = blockIdx.z;
    const float* src = (z == 0) ? x : (z == 1) ? wq : (z == 2) ? wk : wv;
    bf16_t* dst      = (z == 0) ? xb : (z == 1) ? wqb : (z == 2) ? wkb : wvb;
    const size_t cnt8 = (z == 0) ? (BSF / 8) : ((size_t)FDIM * FDIM / 8);
    size_t idx = (size_t)blockIdx.x * 256 + threadIdx.x;
    if (idx >= cnt8) return;
    const float4 a = ((const float4*)src)[idx * 2 + 0];
    const float4 b = ((const float4*)src)[idx * 2 + 1];
    uint4 o;
    o.x = (u32)f2bf(a.x) | ((u32)f2bf(a.y) << 16);
    o.y = (u32)f2bf(a.z) | ((u32)f2bf(a.w) << 16);
    o.z = (u32)f2bf(b.x) | ((u32)f2bf(b.y) << 16);
    o.w = (u32)f2bf(b.z) | ((u32)f2bf(b.w) << 16);
    ((uint4*)dst)[idx] = o;
}

// ---------------------------------------------------------------------------
// kNN v4: exact SET selection via two-level histogram (order-free output —
// the reference only uses nn as a boolean mask, so neighbor order is
// irrelevant; the required set is {33 smallest (dist,idx) keys} \ {min key},
// which exactly reproduces stable argsort[1:33] incl. duplicate-coord
// semantics).
//   One 256-thr block per query; 8 candidates/thread in registers.
//   ib = trunc(dist*8192) (monotonic in dist); coarse bin ib>>8 (64 bins),
//   fine bin ib&255 within the crossing coarse bin. Candidates with
//   ib < IBT are definitely-in (order-free atomic-slot writes, skipping
//   global-min key M); ib == IBT boundary candidates resolved by exact
//   (dist,idx) u64-key min-extraction (full stable-tie semantics).
// LDS ~2.2 KB -> 8 blocks/CU (thread-capped), vs 49 KB/3 blocks before.
// ---------------------------------------------------------------------------
__global__ __launch_bounds__(256) void knn_kernel(const float* __restrict__ coords,
                                                  u16* __restrict__ nn_out) {
    __shared__ u32 chist[64];
    __shared__ u32 fhist[256];
    __shared__ u64 bk[64];                // boundary keys
    __shared__ u64 wpart[4];              // per-wave min-key partials
    __shared__ u32 sc[8];                 // 0:Bc 1:base 2:slot 3:bc 4:IBT
    const int blk = blockIdx.x;           // b*SEQ + qi
    const int b   = blk >> 11;
    const int qi  = blk & (SEQ - 1);
    const int t   = threadIdx.x;
    const int wid = t >> 6, lane = t & 63;
    const size_t qb = (size_t)blk * KNN;

    // zero hists / counters
    fhist[t & 255] = 0;
    if (t < 64) chist[t] = 0;
    if (t == 0) { sc[2] = 0; sc[3] = 0; }

    const float* cb = coords + (size_t)b * SEQ * 3;
    const float qx = cb[qi * 3 + 0];
    const float qy = cb[qi * 3 + 1];
    const float qz = cb[qi * 3 + 2];

    float dist[8];
    int   ib[8];
    u64 tmin = ~0ull;
#pragma unroll
    for (int i = 0; i < 8; ++i) {
        int c = i * 256 + t;
        float dx = __fsub_rn(cb[c * 3 + 0], qx);
        float dy = __fsub_rn(cb[c * 3 + 1], qy);
        float dz = __fsub_rn(cb[c * 3 + 2], qz);
        // numpy order: (dx*dx + dy*dy) + dz*dz, no FMA, IEEE sqrt
        float d2 = __fadd_rn(__fadd_rn(__fmul_rn(dx, dx), __fmul_rn(dy, dy)),
                             __fmul_rn(dz, dz));
        dist[i] = __fsqrt_rn(d2);
        ib[i] = (int)(dist[i] * 8192.0f);            // < 16384 (dist <= sqrt(3))
        u64 key = (((u64)__float_as_uint(dist[i])) << 32) | (u32)c;
        tmin = min_u64(tmin, key);
    }
    // wave-reduce min key
    tmin = min_u64(tmin, shfl_xor_u64(tmin, 1));
    tmin = min_u64(tmin, shfl_xor_u64(tmin, 2));
    tmin = min_u64(tmin, shfl_xor_u64(tmin, 4));
    tmin = min_u64(tmin, shfl_xor_u64(tmin, 8));
    tmin = min_u64(tmin, shfl_xor_u64(tmin, 16));
    tmin = min_u64(tmin, shfl_xor_u64(tmin, 32));
    if (lane == 0) wpart[wid] = tmin;
    __syncthreads();                                  // B1: zeros + wpart

    // coarse histogram
#pragma unroll
    for (int i = 0; i < 8; ++i) atomicAdd(&chist[ib[i] >> 8], 1u);
    const u64 M = min_u64(min_u64(wpart[0], wpart[1]),
                          min_u64(wpart[2], wpart[3]));
    __syncthreads();                                  // B2: coarse done

    // coarse scan (wave 0): find first bin with inclusive-cum >= 33
    if (t < 64) {
        u32 h = chist[t];
        u32 cum = h;
#pragma unroll
        for (int d = 1; d < 64; d <<= 1) {
            u32 v = (u32)__shfl_up((int)cum, d, 64);
            if (t >= d) cum += v;
        }
        u64 bal = __ballot(cum >= 33);
        int Bc = __ffsll((long long)bal) - 1;
        u32 excl = cum - h;
        u32 base = (u32)__shfl((int)excl, Bc, 64);
        if (t == 0) { sc[0] = (u32)Bc; sc[1] = base; }
    }
    __syncthreads();                                  // B3

    // fine histogram inside crossing coarse bin
    {
        const int Bc = (int)sc[0];
#pragma unroll
        for (int i = 0; i < 8; ++i)
            if ((ib[i] >> 8) == Bc) atomicAdd(&fhist[ib[i] & 255], 1u);
    }
    __syncthreads();                                  // B4

    // fine scan (wave 0, 4 bins/lane): find fine crossing bin -> IBT
    if (t < 64) {
        const u32 Bc = sc[0], base = sc[1];
        u32 f0 = fhist[t * 4 + 0], f1 = fhist[t * 4 + 1];
        u32 f2 = fhist[t * 4 + 2], f3 = fhist[t * 4 + 3];
        u32 s = f0 + f1 + f2 + f3;
        u32 cum = s;
#pragma unroll
        for (int d = 1; d < 64; d <<= 1) {
            u32 v = (u32)__shfl_up((int)cum, d, 64);
            if (t >= d) cum += v;
        }
        u32 E = base + (cum - s);                     // exclusive before my 4 bins
        u32 c0 = E + f0, c1 = c0 + f1, c2 = c1 + f2, c3 = c2 + f3;
        u64 bal = __ballot(c3 >= 33);
        int L = __ffsll((long long)bal) - 1;
        if (t == L) {
            int j = (c0 >= 33) ? 0 : (c1 >= 33) ? 1 : (c2 >= 33) ? 2 : 3;
            sc[4] = (Bc << 8) | (u32)(t * 4 + j);     // IBT
        }
    }
    __syncthreads();                                  // B5

    // phase 3: definite-in writes (order-free) + boundary collection
    {
        const int ibt = (int)sc[4];
#pragma unroll
        for (int i = 0; i < 8; ++i) {
            int c = i * 256 + t;
            u64 key = (((u64)__float_as_uint(dist[i])) << 32) | (u32)c;
            if (ib[i] < ibt) {
                if (key != M) {
                    u32 pos = atomicAdd(&sc[2], 1u);
                    nn_out[qb + pos] = (u16)c;
                }
            } else if (ib[i] == ibt) {
                u32 bp = atomicAdd(&sc[3], 1u);
                if (bp < 64) bk[bp] = key;            // cap: pathological only
            }
        }
    }
    __syncthreads();                                  // B6

    // phase 4 (wave 0): exact (dist,idx) selection of remaining slots
    if (t < 64) {
        const u32 m = sc[2];
        const int n = (int)min(sc[3], 64u);
        const int need = 32 - (int)m;                 // >= 0 by construction
        u64 k = (t < n) ? bk[t] : ~0ull;
        if (k == M) k = ~0ull;                        // exclude rank-0 key
#pragma unroll 1
        for (int r = 0; r < need; ++r) {
            u64 g = k;
            g = min_u64(g, shfl_xor_u64(g, 1));
            g = min_u64(g, shfl_xor_u64(g, 2));
            g = min_u64(g, shfl_xor_u64(g, 4));
            g = min_u64(g, shfl_xor_u64(g, 8));
            g = min_u64(g, shfl_xor_u64(g, 16));
            g = min_u64(g, shfl_xor_u64(g, 32));
            if (k == g) {                             // unique holder
                nn_out[qb + m + r] = (u16)(g & 0x7FF);
                k = ~0ull;
            }
        }
    }
}

// ---------------------------------------------------------------------------
// LDS-tiled MFMA GEMM (m93 structure): out[m,n] = sum_k A[m,k]*W[n,k].
// 128x128 block tile, BK=32, 256 thr = 4 waves (2x2), 64x64 wave tile.
// z=0 -> q (fp32 to d_out); z=1,2 -> k,v (bf16 to ws).
// ---------------------------------------------------------------------------
__global__ __launch_bounds__(256) void gemm_mfma(const bf16_t* __restrict__ xb,
                                                 const bf16_t* __restrict__ wqb,
                                                 const bf16_t* __restrict__ wkb,
                                                 const bf16_t* __restrict__ wvb,
                                                 float* __restrict__ qout,
                                                 bf16_t* __restrict__ kvout) {
    __shared__ __align__(16) bf16_t As[128 * 32];
    __shared__ __align__(16) bf16_t Bs[128 * 32];
    const int z = blockIdx.z;
    const bf16_t* W = (z == 0) ? wqb : (z == 1) ? wkb : wvb;
    const int tid  = threadIdx.x;
    const int wid  = tid >> 6, lane = tid & 63;
    const int m16  = lane & 15, quad = lane >> 4;
    const int wm   = (wid & 1) * 64;
    const int wn   = (wid >> 1) * 64;
    const int m0   = blockIdx.y * 128;
    const int n0   = blockIdx.x * 128;

    const int sr = tid >> 2, sc = (tid & 3) * 8;
    const bf16_t* agp = xb + (size_t)(m0 + sr) * FDIM + sc;
    const bf16_t* bgp = W  + (size_t)(n0 + sr) * FDIM + sc;

    f32x4 acc[4][4];
#pragma unroll
    for (int i = 0; i < 4; ++i)
#pragma unroll
        for (int j = 0; j < 4; ++j) acc[i][j] = (f32x4){0.f, 0.f, 0.f, 0.f};

#pragma unroll 1
    for (int k0 = 0; k0 < FDIM; k0 += 32) {
        uint4 a0 = *(const uint4*)(agp + k0);
        uint4 a1 = *(const uint4*)(agp + (size_t)64 * FDIM + k0);
        uint4 b0 = *(const uint4*)(bgp + k0);
        uint4 b1 = *(const uint4*)(bgp + (size_t)64 * FDIM + k0);
        __syncthreads();
        *(uint4*)(As + sr * 32 + sc)        = a0;
        *(uint4*)(As + (sr + 64) * 32 + sc) = a1;
        *(uint4*)(Bs + sr * 32 + sc)        = b0;
        *(uint4*)(Bs + (sr + 64) * 32 + sc) = b1;
        __syncthreads();

        short8 af[4], bfr[4];
#pragma unroll
        for (int i = 0; i < 4; ++i)
            af[i] = *(const short8*)(As + (wm + i * 16 + m16) * 32 + quad * 8);
#pragma unroll
        for (int j = 0; j < 4; ++j)
            bfr[j] = *(const short8*)(Bs + (wn + j * 16 + m16) * 32 + quad * 8);
#pragma unroll
        for (int i = 0; i < 4; ++i)
#pragma unroll
            for (int j = 0; j < 4; ++j)
                acc[i][j] = __builtin_amdgcn_mfma_f32_16x16x32_bf16(af[i], bfr[j],
                                                                    acc[i][j], 0, 0, 0);
    }

    if (z == 0) {
#pragma unroll
        for (int i = 0; i < 4; ++i) {
            const int rowb = m0 + wm + i * 16 + quad * 4;
#pragma unroll
            for (int r = 0; r < 4; ++r) {
                float* orow = qout + (size_t)(rowb + r) * FDIM + n0 + wn + m16;
                orow[ 0] = acc[i][0][r]; orow[16] = acc[i][1][r];
                orow[32] = acc[i][2][r]; orow[48] = acc[i][3][r];
            }
        }
    } else {
        bf16_t* base = kvout + (size_t)(z - 1) * BSF;
#pragma unroll
        for (int i = 0; i < 4; ++i) {
            const int rowb = m0 + wm + i * 16 + quad * 4;
#pragma unroll
            for (int r = 0; r < 4; ++r) {
                bf16_t* orow = base + (size_t)(rowb + r) * FDIM + n0 + wn + m16;
                orow[ 0] = f2bf(acc[i][0][r]); orow[16] = f2bf(acc[i][1][r]);
                orow[32] = f2bf(acc[i][2][r]); orow[48] = f2bf(acc[i][3][r]);
            }
        }
    }
}

// ---------------------------------------------------------------------------
// Attention v3: BARRIER-FREE. One wave per (query, head); 256-thr blocks =
// 4 independent waves; no __syncthreads. nn indices + softmax weights live
// in registers and move via shuffles; q slice in a private per-wave LDS slot.
// XCD swizzle kept (bijective). HW-validated in r13.
// ---------------------------------------------------------------------------
__global__ __launch_bounds__(256) void attn_kernel(const bf16_t* __restrict__ kv,
                                                   const u16* __restrict__ nn,
                                                   float* __restrict__ out) {
    __shared__ float qsl[4][64];                          // 1 KB, per-wave slot
    const int i   = blockIdx.x;                           // 0..16383
    const int b   = (i & 7) >> 1;                         // XCD pair -> batch
    const int jb  = ((i >> 3) << 1) | (i & 1);            // 0..4095, bijective
    const int tid = threadIdx.x;
    const int wid = tid >> 6, lane = tid & 63;
    const int gid = (jb << 2) | wid;                      // 0..16383 per batch
    const int qi  = gid >> 3, h = gid & 7;
    const int blk = (b << 11) | qi;

    int sreg = 0;
    if (lane < KNN) sreg = (int)nn[(size_t)blk * KNN + lane] & (SEQ - 1);
    qsl[wid][lane] = out[(size_t)blk * FDIM + h * HDIM + lane];   // own q slice
    __asm__ volatile("s_waitcnt lgkmcnt(0)" ::: "memory");
    __builtin_amdgcn_wave_barrier();

    // ---- QK: 2 lanes per neighbor (j, half), 32 dims each ----
    const int j = lane & 31, half = lane >> 5;
    const int rowj = __shfl(sreg, j, 64);
    const bf16_t* kreg = kv + ((size_t)((b << 11) + rowj)) * FDIM + h * HDIM + half * 32;
    const float* qp = &qsl[wid][half * 32];
    float acc = 0.f;
#pragma unroll
    for (int d = 0; d < 32; d += 8) {
        uint4 kvv = *(const uint4*)(kreg + d);   // 8 bf16
        float f0, f1, f2, f3, f4, f5, f6, f7;
        bf2x2(kvv.x, f0, f1); bf2x2(kvv.y, f2, f3);
        bf2x2(kvv.z, f4, f5); bf2x2(kvv.w, f6, f7);
        acc += qp[d + 0] * f0 + qp[d + 1] * f1 + qp[d + 2] * f2 + qp[d + 3] * f3
             + qp[d + 4] * f4 + qp[d + 5] * f5 + qp[d + 6] * f6 + qp[d + 7] * f7;
    }
    acc += __shfl_xor(acc, 32, 64);
    float s = acc * 0.125f;                 // 1/sqrt(64)
    float m = s;
    m = fmaxf(m, __shfl_xor(m, 1, 64));
    m = fmaxf(m, __shfl_xor(m, 2, 64));
    m = fmaxf(m, __shfl_xor(m, 4, 64));
    m = fmaxf(m, __shfl_xor(m, 8, 64));
    m = fmaxf(m, __shfl_xor(m, 16, 64));
    float e = __expf(s - m);
    float sum = e;
    sum += __shfl_xor(sum, 1, 64);
    sum += __shfl_xor(sum, 2, 64);
    sum += __shfl_xor(sum, 4, 64);
    sum += __shfl_xor(sum, 8, 64);
    sum += __shfl_xor(sum, 16, 64);
    float w = e / sum;                      // valid per j on lanes j and j+32

    // ---- PV: g = neighbor-group of 8, l = dim-quad (4 dims via uint2) ----
    const int g = lane >> 4, l = lane & 15;
    const bf16_t* vbase = kv + BSF + ((size_t)(b << 11)) * FDIM + h * HDIM + l * 4;
    float o0 = 0.f, o1 = 0.f, o2 = 0.f, o3 = 0.f;
#pragma unroll
    for (int t2 = 0; t2 < 8; ++t2) {
        const int j2 = (g << 3) | t2;
        const float wj = __shfl(w, j2, 64);
        const int row = __shfl(sreg, j2, 64);
        uint2 vv = *(const uint2*)(vbase + (size_t)row * FDIM);   // 4 bf16
        float f0, f1, f2, f3;
        bf2x2(vv.x, f0, f1); bf2x2(vv.y, f2, f3);
        o0 += wj * f0; o1 += wj * f1; o2 += wj * f2; o3 += wj * f3;
    }
    o0 += __shfl_xor(o0, 16, 64); o0 += __shfl_xor(o0, 32, 64);
    o1 += __shfl_xor(o1, 16, 64); o1 += __shfl_xor(o1, 32, 64);
    o2 += __shfl_xor(o2, 16, 64); o2 += __shfl_xor(o2, 32, 64);
    o3 += __shfl_xor(o3, 16, 64); o3 += __shfl_xor(o3, 32, 64);
    if (g == 0) {
        float4 ov = make_float4(o0, o1, o2, o3);
        *(float4*)(out + (size_t)blk * FDIM + h * HDIM + l * 4) = ov;
    }
}

// ---------------------------------------------------------------------------
// metric = mean_s(k) = (mean_s x) @ Wk^T  (linearity), fp32 from raw inputs
// ---------------------------------------------------------------------------
__global__ __launch_bounds__(256) void xbar_kernel(const float* __restrict__ x,
                                                   float* __restrict__ xbar) {
    const int b = blockIdx.x, chunk = blockIdx.y;   // 32 chunks of 64 rows
    const int tid = threadIdx.x;
    const float* xp = x + (size_t)b * SF + (size_t)chunk * 64 * FDIM;
    float s0 = 0.f, s1 = 0.f;
    for (int r = 0; r < 64; ++r) {
        s0 += xp[(size_t)r * FDIM + tid];
        s1 += xp[(size_t)r * FDIM + tid + 256];
    }
    atomicAdd(&xbar[b * FDIM + tid],       s0 * (1.f / 2048.f));
    atomicAdd(&xbar[b * FDIM + tid + 256], s1 * (1.f / 2048.f));
}

__global__ __launch_bounds__(256) void metric_kernel(const float* __restrict__ xbar,
                                                     const float* __restrict__ Wk,
                                                     float* __restrict__ metric) {
    const int o = blockIdx.x * 256 + threadIdx.x;   // 2048 outputs
    const int b = o >> 9, f = o & 511;
    const float* xb = xbar + b * FDIM;
    const float* wr = Wk + (size_t)f * FDIM;
    float acc = 0.f;
#pragma unroll 4
    for (int kk = 0; kk < FDIM; kk += 4) {
        float4 wv = *(const float4*)(wr + kk);
        acc += xb[kk + 0] * wv.x + xb[kk + 1] * wv.y
             + xb[kk + 2] * wv.z + xb[kk + 3] * wv.w;
    }
    metric[o] = acc;
}

// ---------------------------------------------------------------------------
extern "C" void kernel_launch(void* const* d_in, const int* in_sizes, int n_in,
                              void* d_out, int out_size, void* d_ws, size_t ws_size,
                              hipStream_t stream) {
    const float* x      = (const float*)d_in[0];
    const float* coords = (const float*)d_in[1];
    const float* Wq     = (const float*)d_in[2];
    const float* Wk     = (const float*)d_in[3];
    const float* Wv     = (const float*)d_in[4];
    float* out    = (float*)d_out;
    float* metric = out + BSF;

    // ws layout (26.0 MiB):
    //   xb bf16 BSF (8 MiB) | wqb/wkb/wvb bf16 (1.5 MiB) | kv bf16 2*BSF (16 MiB)
    //   | nn u16 (0.5 MiB) | xbar f32 (8 KiB)
    char* p = (char*)d_ws;
    bf16_t* xb   = (bf16_t*)p;                       p += BSF * sizeof(bf16_t);
    bf16_t* wqb  = (bf16_t*)p;                       p += (size_t)FDIM * FDIM * sizeof(bf16_t);
    bf16_t* wkb  = (bf16_t*)p;                       p += (size_t)FDIM * FDIM * sizeof(bf16_t);
    bf16_t* wvb  = (bf16_t*)p;                       p += (size_t)FDIM * FDIM * sizeof(bf16_t);
    bf16_t* kv   = (bf16_t*)p;                       p += 2 * BSF * sizeof(bf16_t);
    u16*    nn   = (u16*)p;                          p += (size_t)BATCH * SEQ * KNN * sizeof(u16);
    float*  xbar = (float*)p;

    cast_kernel<<<dim3(BSF / 8 / 256, 1, 4), 256, 0, stream>>>(x, Wq, Wk, Wv,
                                                               xb, wqb, wkb, wvb);
    knn_kernel<<<BATCH * SEQ, 256, 0, stream>>>(coords, nn);

    // q -> d_out (fp32), k/v -> ws (bf16); one dispatch, 128x128 tiles
    gemm_mfma<<<dim3(FDIM / 128, (BATCH * SEQ) / 128, 3), 256, 0, stream>>>(
        xb, wqb, wkb, wvb, out, kv);

    hipMemsetAsync(xbar, 0, BATCH * FDIM * sizeof(float), stream);
    xbar_kernel<<<dim3(BATCH, 32), 256, 0, stream>>>(x, xbar);
    metric_kernel<<<(BATCH * NHEAD * HDIM) / 256, 256, 0, stream>>>(xbar, Wk, metric);

    attn_kernel<<<(BATCH * SEQ * NHEAD) / 4, 256, 0, stream>>>(kv, nn, out);
}